// Round 1
// baseline (2095.024 us; speedup 1.0000x reference)
//
#include <hip/hip_runtime.h>
#include <math.h>

#define BDIM 8
#define CDIM 256
#define NDIM 2048
#define MDIM 4096
#define KNN 10

__device__ __forceinline__ float f4get(const float4& v, int i) { return (&v.x)[i]; }

// ---------------------------------------------------------------------------
// K1: y = Wqk*x ; v = Wv*x + bv      (per batch: [256x256]*[256x2048])
// grid (N/64, C/64, B), 256 threads, 64x64 tile, 4x4 microtile, k-chunk 16
// ---------------------------------------------------------------------------
__global__ __launch_bounds__(256)
void k_qkv(const float* __restrict__ x, const float* __restrict__ Wqk,
           const float* __restrict__ Wv, const float* __restrict__ bv,
           float* __restrict__ y, float* __restrict__ v)
{
    const int nt = blockIdx.x, ct = blockIdx.y, b = blockIdx.z;
    const int tid = threadIdx.x, tx = tid & 15, ty = tid >> 4;
    const int n0 = nt * 64, c0 = ct * 64;
    __shared__ float wq_s[64][20], wv_s[64][20], x_s[16][64];
    float accy[4][4] = {}, accv[4][4] = {};
    const int wr = tid >> 2, wc = (tid & 3) * 4;
    const int sr = tid >> 4, sc = (tid & 15) * 4;
    for (int ck = 0; ck < CDIM; ck += 16) {
        *(float4*)&wq_s[wr][wc] = *(const float4*)&Wqk[(size_t)(c0 + wr) * CDIM + ck + wc];
        *(float4*)&wv_s[wr][wc] = *(const float4*)&Wv[(size_t)(c0 + wr) * CDIM + ck + wc];
        *(float4*)&x_s[sr][sc] = *(const float4*)&x[((size_t)b * CDIM + ck + sr) * NDIM + n0 + sc];
        __syncthreads();
#pragma unroll
        for (int c4 = 0; c4 < 4; ++c4) {
            float4 wq4[4], wv4[4];
#pragma unroll
            for (int i = 0; i < 4; ++i) {
                wq4[i] = *(const float4*)&wq_s[ty * 4 + i][c4 * 4];
                wv4[i] = *(const float4*)&wv_s[ty * 4 + i][c4 * 4];
            }
#pragma unroll
            for (int l = 0; l < 4; ++l) {
                float4 xl = *(const float4*)&x_s[c4 * 4 + l][tx * 4];
#pragma unroll
                for (int i = 0; i < 4; ++i) {
                    float wq_il = f4get(wq4[i], l), wv_il = f4get(wv4[i], l);
#pragma unroll
                    for (int j = 0; j < 4; ++j) {
                        accy[i][j] += wq_il * f4get(xl, j);
                        accv[i][j] += wv_il * f4get(xl, j);
                    }
                }
            }
        }
        __syncthreads();
    }
#pragma unroll
    for (int i = 0; i < 4; ++i) {
        size_t off = ((size_t)b * CDIM + c0 + ty * 4 + i) * NDIM + n0 + tx * 4;
        float bvv = bv[c0 + ty * 4 + i];
        *(float4*)&y[off] = make_float4(accy[i][0], accy[i][1], accy[i][2], accy[i][3]);
        *(float4*)&v[off] = make_float4(accv[i][0] + bvv, accv[i][1] + bvv,
                                        accv[i][2] + bvv, accv[i][3] + bvv);
    }
}

// ---------------------------------------------------------------------------
// K2: row softmax stats of energy = Y^T Y.  grid (N/64, B). Online max/sum
// per thread over its column subset; single cross-thread merge at the end.
// ---------------------------------------------------------------------------
__global__ __launch_bounds__(256)
void k_rowstats(const float* __restrict__ y, float* __restrict__ rowmax,
                float* __restrict__ rowsum)
{
    const int nt = blockIdx.x, b = blockIdx.y;
    const int tid = threadIdx.x, tx = tid & 15, ty = tid >> 4;
    const int n0 = nt * 64;
    const float* yb = y + (size_t)b * CDIM * NDIM;
    __shared__ float yn_s[16][64], ym_s[16][64];
    __shared__ float smax[64][16], ssum[64][16];
    float pmax[4], psum[4];
#pragma unroll
    for (int i = 0; i < 4; ++i) { pmax[i] = -3.4e38f; psum[i] = 0.f; }
    const int sr = tid >> 4, sc = (tid & 15) * 4;
    for (int mt = 0; mt < NDIM / 64; ++mt) {
        const int m0 = mt * 64;
        float acc[4][4] = {};
        for (int ck = 0; ck < CDIM; ck += 16) {
            *(float4*)&yn_s[sr][sc] = *(const float4*)&yb[(size_t)(ck + sr) * NDIM + n0 + sc];
            *(float4*)&ym_s[sr][sc] = *(const float4*)&yb[(size_t)(ck + sr) * NDIM + m0 + sc];
            __syncthreads();
#pragma unroll
            for (int cc = 0; cc < 16; ++cc) {
                float4 a4 = *(const float4*)&yn_s[cc][ty * 4];
                float4 b4 = *(const float4*)&ym_s[cc][tx * 4];
#pragma unroll
                for (int i = 0; i < 4; ++i)
#pragma unroll
                    for (int j = 0; j < 4; ++j)
                        acc[i][j] += f4get(a4, i) * f4get(b4, j);
            }
            __syncthreads();
        }
#pragma unroll
        for (int i = 0; i < 4; ++i) {
            float tmax = fmaxf(fmaxf(acc[i][0], acc[i][1]), fmaxf(acc[i][2], acc[i][3]));
            float nm = fmaxf(pmax[i], tmax);
            float s = psum[i] * __expf(pmax[i] - nm);
#pragma unroll
            for (int j = 0; j < 4; ++j) s += __expf(acc[i][j] - nm);
            psum[i] = s; pmax[i] = nm;
        }
    }
#pragma unroll
    for (int i = 0; i < 4; ++i) { smax[ty * 4 + i][tx] = pmax[i]; ssum[ty * 4 + i][tx] = psum[i]; }
    __syncthreads();
    if (tid < 64) {
        float Mx = -3.4e38f;
#pragma unroll
        for (int t = 0; t < 16; ++t) Mx = fmaxf(Mx, smax[tid][t]);
        float S = 0.f;
#pragma unroll
        for (int t = 0; t < 16; ++t) S += ssum[tid][t] * __expf(smax[tid][t] - Mx);
        rowmax[(size_t)b * NDIM + n0 + tid] = Mx;
        rowsum[(size_t)b * NDIM + n0 + tid] = S;
    }
}

// ---------------------------------------------------------------------------
// K3: recompute energy per (m-tile, n-tile), attn = exp(e-rmax)/rsum,
// accumulate colsum[m] and xr_num[c,m] = sum_n v[c,n]*attn[n,m]; at the end
// xr = xr_num / (1e-9 + colsum).  grid (N/64, B), persistent 256x64 output.
// ---------------------------------------------------------------------------
__global__ __launch_bounds__(256)
void k_attn_xr(const float* __restrict__ y, const float* __restrict__ v,
               const float* __restrict__ rowmax, const float* __restrict__ rowsum,
               float* __restrict__ xr)
{
    const int mt = blockIdx.x, b = blockIdx.y;
    const int tid = threadIdx.x, tx = tid & 15, ty = tid >> 4;
    const int m0 = mt * 64;
    const float* yb = y + (size_t)b * CDIM * NDIM;
    const float* vb = v + (size_t)b * CDIM * NDIM;
    __shared__ float yn_s[16][64], ym_s[16][64];
    __shared__ float attn_s[64][68];
    __shared__ float v_s[16][256];
    __shared__ float cred[16][64];
    __shared__ float colinv[64];
    float xracc[16][4] = {};
    float csum[4] = {0.f, 0.f, 0.f, 0.f};
    const int sr = tid >> 4, sc = (tid & 15) * 4;
    for (int ntl = 0; ntl < NDIM / 64; ++ntl) {
        const int n0 = ntl * 64;
        float acc[4][4] = {};
        for (int ck = 0; ck < CDIM; ck += 16) {
            *(float4*)&yn_s[sr][sc] = *(const float4*)&yb[(size_t)(ck + sr) * NDIM + n0 + sc];
            *(float4*)&ym_s[sr][sc] = *(const float4*)&yb[(size_t)(ck + sr) * NDIM + m0 + sc];
            __syncthreads();
#pragma unroll
            for (int cc = 0; cc < 16; ++cc) {
                float4 a4 = *(const float4*)&yn_s[cc][ty * 4];
                float4 b4 = *(const float4*)&ym_s[cc][tx * 4];
#pragma unroll
                for (int i = 0; i < 4; ++i)
#pragma unroll
                    for (int j = 0; j < 4; ++j)
                        acc[i][j] += f4get(a4, i) * f4get(b4, j);
            }
            __syncthreads();
        }
        float av[4][4];
#pragma unroll
        for (int i = 0; i < 4; ++i) {
            float rmx = rowmax[(size_t)b * NDIM + n0 + ty * 4 + i];
            float inv = 1.0f / rowsum[(size_t)b * NDIM + n0 + ty * 4 + i];
#pragma unroll
            for (int j = 0; j < 4; ++j) {
                float a_ = __expf(acc[i][j] - rmx) * inv;
                av[i][j] = a_;
                csum[j] += a_;
            }
        }
#pragma unroll
        for (int i = 0; i < 4; ++i)
            *(float4*)&attn_s[ty * 4 + i][tx * 4] =
                make_float4(av[i][0], av[i][1], av[i][2], av[i][3]);
        __syncthreads();
#pragma unroll 1
        for (int nc = 0; nc < 4; ++nc) {
            // stage v[c=0..255][n0+nc*16 .. +16] transposed into v_s[nn][c]
#pragma unroll
            for (int q = 0; q < 4; ++q) {
                float4 vv = *(const float4*)&vb[(size_t)tid * NDIM + n0 + nc * 16 + q * 4];
                v_s[q * 4 + 0][tid] = vv.x; v_s[q * 4 + 1][tid] = vv.y;
                v_s[q * 4 + 2][tid] = vv.z; v_s[q * 4 + 3][tid] = vv.w;
            }
            __syncthreads();
#pragma unroll
            for (int nn = 0; nn < 16; ++nn) {
                float4 a4 = *(const float4*)&attn_s[nc * 16 + nn][tx * 4];
#pragma unroll
                for (int i4 = 0; i4 < 4; ++i4) {
                    float4 vf = *(const float4*)&v_s[nn][ty * 16 + i4 * 4];
#pragma unroll
                    for (int k = 0; k < 4; ++k)
#pragma unroll
                        for (int j = 0; j < 4; ++j)
                            xracc[i4 * 4 + k][j] += f4get(vf, k) * f4get(a4, j);
                }
            }
            __syncthreads();
        }
    }
#pragma unroll
    for (int j = 0; j < 4; ++j) cred[ty][tx * 4 + j] = csum[j];
    __syncthreads();
    if (tid < 64) {
        float s = 0.f;
#pragma unroll
        for (int t = 0; t < 16; ++t) s += cred[t][tid];
        colinv[tid] = 1.0f / (1e-9f + s);
    }
    __syncthreads();
    float ci[4];
#pragma unroll
    for (int j = 0; j < 4; ++j) ci[j] = colinv[tx * 4 + j];
#pragma unroll
    for (int i = 0; i < 16; ++i) {
        size_t off = ((size_t)b * CDIM + ty * 16 + i) * NDIM + m0 + tx * 4;
        *(float4*)&xr[off] = make_float4(xracc[i][0] * ci[0], xracc[i][1] * ci[1],
                                         xracc[i][2] * ci[2], xracc[i][3] * ci[3]);
    }
}

// ---------------------------------------------------------------------------
// K4a: t = Wt*(x - xr) + bt ; bn ; feat = x + relu(bn)
// ---------------------------------------------------------------------------
__global__ __launch_bounds__(256)
void k_tbn(const float* __restrict__ x, const float* __restrict__ xr,
           const float* __restrict__ Wt, const float* __restrict__ bt,
           const float* __restrict__ gamma, const float* __restrict__ beta,
           float* __restrict__ feat)
{
    const int nt = blockIdx.x, ct = blockIdx.y, b = blockIdx.z;
    const int tid = threadIdx.x, tx = tid & 15, ty = tid >> 4;
    const int n0 = nt * 64, c0 = ct * 64;
    __shared__ float w_s[64][20], d_s[16][64];
    float acc[4][4] = {};
    const int wr = tid >> 2, wc = (tid & 3) * 4;
    const int sr = tid >> 4, sc = (tid & 15) * 4;
    for (int ck = 0; ck < CDIM; ck += 16) {
        *(float4*)&w_s[wr][wc] = *(const float4*)&Wt[(size_t)(c0 + wr) * CDIM + ck + wc];
        size_t doff = ((size_t)b * CDIM + ck + sr) * NDIM + n0 + sc;
        float4 xv = *(const float4*)&x[doff];
        float4 rv = *(const float4*)&xr[doff];
        *(float4*)&d_s[sr][sc] = make_float4(xv.x - rv.x, xv.y - rv.y, xv.z - rv.z, xv.w - rv.w);
        __syncthreads();
#pragma unroll
        for (int c4 = 0; c4 < 4; ++c4) {
            float4 w4[4];
#pragma unroll
            for (int i = 0; i < 4; ++i) w4[i] = *(const float4*)&w_s[ty * 4 + i][c4 * 4];
#pragma unroll
            for (int l = 0; l < 4; ++l) {
                float4 xl = *(const float4*)&d_s[c4 * 4 + l][tx * 4];
#pragma unroll
                for (int i = 0; i < 4; ++i) {
                    float wil = f4get(w4[i], l);
#pragma unroll
                    for (int j = 0; j < 4; ++j) acc[i][j] += wil * f4get(xl, j);
                }
            }
        }
        __syncthreads();
    }
    const float bnsc = 0.99999500003749968f; // 1/sqrt(1 + 1e-5)
#pragma unroll
    for (int i = 0; i < 4; ++i) {
        int co = c0 + ty * 4 + i;
        float g = gamma[co] * bnsc, be = beta[co], bb = bt[co];
        size_t off = ((size_t)b * CDIM + co) * NDIM + n0 + tx * 4;
        float4 xv = *(const float4*)&x[off];
        float4 o;
#pragma unroll
        for (int j = 0; j < 4; ++j)
            (&o.x)[j] = f4get(xv, j) + fmaxf((acc[i][j] + bb) * g + be, 0.f);
        *(float4*)&feat[off] = o;
    }
}

// ---------------------------------------------------------------------------
// K4b: query = Wproj*feat + bproj   (3x256 x 256x2048 per batch)
// ---------------------------------------------------------------------------
__global__ __launch_bounds__(256)
void k_query(const float* __restrict__ feat, const float* __restrict__ Wp,
             const float* __restrict__ bp, float* __restrict__ query)
{
    __shared__ float wp_s[3 * CDIM];
    const int tid = threadIdx.x, b = blockIdx.y;
    for (int i = tid; i < 3 * CDIM; i += 256) wp_s[i] = Wp[i];
    __syncthreads();
    const int n = blockIdx.x * 256 + tid;
    float a0 = 0.f, a1 = 0.f, a2 = 0.f;
    const float* fb = feat + (size_t)b * CDIM * NDIM + n;
    for (int c = 0; c < CDIM; ++c) {
        float f = fb[(size_t)c * NDIM];
        a0 += wp_s[c] * f;
        a1 += wp_s[CDIM + c] * f;
        a2 += wp_s[2 * CDIM + c] * f;
    }
    query[((size_t)b * 3 + 0) * NDIM + n] = a0 + bp[0];
    query[((size_t)b * 3 + 1) * NDIM + n] = a1 + bp[1];
    query[((size_t)b * 3 + 2) * NDIM + n] = a2 + bp[2];
}

// ---------------------------------------------------------------------------
// K5: soft projection — KNN(K=10) over M=4096 per query + softmax-weighted sum
// grid (N/256, B), 256 threads, point cloud + |p|^2 in LDS (64 KB)
// ---------------------------------------------------------------------------
__global__ __launch_bounds__(256)
void k_softproj(const float* __restrict__ pc, const float* __restrict__ query,
                const float* __restrict__ temp_p, float* __restrict__ out)
{
    __shared__ float px[MDIM], py[MDIM], pz[MDIM], p2[MDIM];
    const int tid = threadIdx.x, b = blockIdx.y;
    const float* pb = pc + (size_t)b * 3 * MDIM;
    for (int i = tid; i < MDIM; i += 256) {
        float a = pb[i], c = pb[MDIM + i], d = pb[2 * MDIM + i];
        px[i] = a; py[i] = c; pz[i] = d;
        p2[i] = a * a + c * c + d * d;
    }
    __syncthreads();
    const int n = blockIdx.x * 256 + tid;
    const float qx = query[((size_t)b * 3 + 0) * NDIM + n];
    const float qy = query[((size_t)b * 3 + 1) * NDIM + n];
    const float qz = query[((size_t)b * 3 + 2) * NDIM + n];
    const float q2 = qx * qx + qy * qy + qz * qz;
    float bd[KNN];
    int bi[KNN];
#pragma unroll
    for (int k = 0; k < KNN; ++k) { bd[k] = 3.4e38f; bi[k] = 0; }
    for (int m = 0; m < MDIM; ++m) {
        float d2 = q2 + p2[m] - 2.0f * (qx * px[m] + qy * py[m] + qz * pz[m]);
        if (d2 < bd[KNN - 1]) {
            bd[KNN - 1] = d2; bi[KNN - 1] = m;
#pragma unroll
            for (int k = KNN - 1; k > 0; --k) {
                if (bd[k] < bd[k - 1]) {
                    float td = bd[k]; bd[k] = bd[k - 1]; bd[k - 1] = td;
                    int ti = bi[k]; bi[k] = bi[k - 1]; bi[k - 1] = ti;
                }
            }
        }
    }
    const float temp = temp_p[0];
    const float sigma = fmaxf(temp * temp, 1e-4f) + 1e-8f;
    const float inv_sig = 1.0f / sigma;
    float gx[KNN], gy[KNN], gz[KNN], dist[KNN];
#pragma unroll
    for (int k = 0; k < KNN; ++k) {
        int m = bi[k];
        gx[k] = px[m]; gy[k] = py[m]; gz[k] = pz[m];
        float dx = gx[k] - qx, dy = gy[k] - qy, dz = gz[k] - qz;
        dist[k] = (dx * dx + dy * dy + dz * dz) * inv_sig;
    }
    float mn = dist[0];
#pragma unroll
    for (int k = 1; k < KNN; ++k) mn = fminf(mn, dist[k]);
    float wsum = 0.f, ox = 0.f, oy = 0.f, oz = 0.f;
#pragma unroll
    for (int k = 0; k < KNN; ++k) {
        float w = __expf(mn - dist[k]);
        wsum += w; ox += w * gx[k]; oy += w * gy[k]; oz += w * gz[k];
    }
    float invw = 1.0f / wsum;
    out[((size_t)b * 3 + 0) * NDIM + n] = ox * invw;
    out[((size_t)b * 3 + 1) * NDIM + n] = oy * invw;
    out[((size_t)b * 3 + 2) * NDIM + n] = oz * invw;
}

// ---------------------------------------------------------------------------
extern "C" void kernel_launch(void* const* d_in, const int* in_sizes, int n_in,
                              void* d_out, int out_size, void* d_ws, size_t ws_size,
                              hipStream_t stream)
{
    const float* x     = (const float*)d_in[0];
    const float* pc    = (const float*)d_in[1];
    const float* Wqk   = (const float*)d_in[2];
    const float* Wv    = (const float*)d_in[3];
    const float* bv    = (const float*)d_in[4];
    const float* Wt    = (const float*)d_in[5];
    const float* bt    = (const float*)d_in[6];
    const float* gamma = (const float*)d_in[7];
    const float* beta  = (const float*)d_in[8];
    const float* Wp    = (const float*)d_in[9];
    const float* bp    = (const float*)d_in[10];
    const float* temp  = (const float*)d_in[11];
    float* out = (float*)d_out;

    float* ws = (float*)d_ws;
    const size_t SZ = (size_t)BDIM * CDIM * NDIM;     // 4,194,304 floats
    float* y      = ws;                // 16 MB
    float* v      = ws + SZ;           // 16 MB
    float* xr     = ws + 2 * SZ;       // 16 MB
    float* rowmax = ws + 3 * SZ;       // B*N
    float* rowsum = rowmax + (size_t)BDIM * NDIM;
    float* query  = rowsum + (size_t)BDIM * NDIM;     // B*3*N
    float* feat   = y;                 // alias: y dead after k_attn_xr

    k_qkv<<<dim3(NDIM / 64, CDIM / 64, BDIM), 256, 0, stream>>>(x, Wqk, Wv, bv, y, v);
    k_rowstats<<<dim3(NDIM / 64, BDIM), 256, 0, stream>>>(y, rowmax, rowsum);
    k_attn_xr<<<dim3(NDIM / 64, BDIM), 256, 0, stream>>>(y, v, rowmax, rowsum, xr);
    k_tbn<<<dim3(NDIM / 64, CDIM / 64, BDIM), 256, 0, stream>>>(x, xr, Wt, bt, gamma, beta, feat);
    k_query<<<dim3(NDIM / 256, BDIM), 256, 0, stream>>>(feat, Wp, bp, query);
    k_softproj<<<dim3(NDIM / 256, BDIM), 256, 0, stream>>>(pc, query, temp, out);
}

// Round 2
// 1115.344 us; speedup vs baseline: 1.8784x; 1.8784x over previous
//
#include <hip/hip_runtime.h>
#include <math.h>

#define BDIM 8
#define CDIM 256
#define NDIM 2048
#define MDIM 4096
#define KNN 10

typedef _Float16 f16;
typedef f16  f16x8 __attribute__((ext_vector_type(8)));
typedef f16  f16x4 __attribute__((ext_vector_type(4)));
typedef float f32x4 __attribute__((ext_vector_type(4)));

__device__ __forceinline__ float f4get(const float4& v, int i) { return (&v.x)[i]; }

__device__ __forceinline__ f32x4 mfma16(f16x8 a, f16x8 b, f32x4 c) {
    return __builtin_amdgcn_mfma_f32_16x16x32_f16(a, b, c, 0, 0, 0);
}

// ---------------------------------------------------------------------------
// K1: y = Wqk*x ; v = Wv*x + bv  (fp32 vector GEMM; epilogue emits fp16)
// outputs: yt[b][n][c] fp16 (transposed), vh[b][c][n] fp16
// ---------------------------------------------------------------------------
__global__ __launch_bounds__(256)
void k_qkv(const float* __restrict__ x, const float* __restrict__ Wqk,
           const float* __restrict__ Wv, const float* __restrict__ bv,
           f16* __restrict__ yt, f16* __restrict__ vh)
{
    const int nt = blockIdx.x, ct = blockIdx.y, b = blockIdx.z;
    const int tid = threadIdx.x, tx = tid & 15, ty = tid >> 4;
    const int n0 = nt * 64, c0 = ct * 64;
    __shared__ float wq_s[64][20], wv_s[64][20], x_s[16][64];
    float accy[4][4] = {}, accv[4][4] = {};
    const int wr = tid >> 2, wc = (tid & 3) * 4;
    const int sr = tid >> 4, sc = (tid & 15) * 4;
    for (int ck = 0; ck < CDIM; ck += 16) {
        *(float4*)&wq_s[wr][wc] = *(const float4*)&Wqk[(size_t)(c0 + wr) * CDIM + ck + wc];
        *(float4*)&wv_s[wr][wc] = *(const float4*)&Wv[(size_t)(c0 + wr) * CDIM + ck + wc];
        *(float4*)&x_s[sr][sc] = *(const float4*)&x[((size_t)b * CDIM + ck + sr) * NDIM + n0 + sc];
        __syncthreads();
#pragma unroll
        for (int c4 = 0; c4 < 4; ++c4) {
            float4 wq4[4], wv4[4];
#pragma unroll
            for (int i = 0; i < 4; ++i) {
                wq4[i] = *(const float4*)&wq_s[ty * 4 + i][c4 * 4];
                wv4[i] = *(const float4*)&wv_s[ty * 4 + i][c4 * 4];
            }
#pragma unroll
            for (int l = 0; l < 4; ++l) {
                float4 xl = *(const float4*)&x_s[c4 * 4 + l][tx * 4];
#pragma unroll
                for (int i = 0; i < 4; ++i) {
                    float wq_il = f4get(wq4[i], l), wv_il = f4get(wv4[i], l);
#pragma unroll
                    for (int j = 0; j < 4; ++j) {
                        accy[i][j] += wq_il * f4get(xl, j);
                        accv[i][j] += wv_il * f4get(xl, j);
                    }
                }
            }
        }
        __syncthreads();
    }
    // yt[b][n][c]: for each of 4 n, write 4 contiguous c as fp16 (8B store)
#pragma unroll
    for (int j = 0; j < 4; ++j) {
        f16x4 p;
#pragma unroll
        for (int i = 0; i < 4; ++i) p[i] = (f16)accy[i][j];
        *(f16x4*)&yt[((size_t)b * NDIM + n0 + tx * 4 + j) * CDIM + c0 + ty * 4] = p;
    }
    // vh[b][c][n]: for each of 4 c, write 4 contiguous n as fp16
#pragma unroll
    for (int i = 0; i < 4; ++i) {
        float bvv = bv[c0 + ty * 4 + i];
        f16x4 p;
#pragma unroll
        for (int j = 0; j < 4; ++j) p[j] = (f16)(accv[i][j] + bvv);
        *(f16x4*)&vh[((size_t)b * CDIM + c0 + ty * 4 + i) * NDIM + n0 + tx * 4] = p;
    }
}

// ---------------------------------------------------------------------------
// K2 (MFMA): row softmax stats of E = Y^T Y using symmetry: block owns rows
// m0..m0+31 and sweeps all n computing E[n][m] = E[m][n]. Online max/sum.
// grid (N/32, B), 256 thr = 4 waves, waves split the n sweep.
// ---------------------------------------------------------------------------
__global__ __launch_bounds__(256)
void k_rowstats(const f16* __restrict__ yt, float* __restrict__ rowmax,
                float* __restrict__ rowsum)
{
    const int mt = blockIdx.x, b = blockIdx.y;
    const int wave = threadIdx.x >> 6, lane = threadIdx.x & 63;
    const int m0 = mt * 32;
    const int row = lane & 15, kq = lane >> 4;
    const f16* ytb = yt + (size_t)b * NDIM * CDIM;
    // persistent B-frags: rows m0..m0+31, all 256 c (2 mtiles x 8 ksteps)
    f16x8 Bf[2][8];
#pragma unroll
    for (int mm = 0; mm < 2; ++mm)
#pragma unroll
        for (int k = 0; k < 8; ++k)
            Bf[mm][k] = *(const f16x8*)&ytb[(size_t)(m0 + mm * 16 + row) * CDIM + k * 32 + kq * 8];
    float mx[2] = {-3.4e38f, -3.4e38f}, sm[2] = {0.f, 0.f};
    for (int it = wave; it < NDIM / 16; it += 4) {
        const int n0 = it * 16;
        f32x4 acc[2] = {{0.f, 0.f, 0.f, 0.f}, {0.f, 0.f, 0.f, 0.f}};
#pragma unroll
        for (int k = 0; k < 8; ++k) {
            f16x8 Af = *(const f16x8*)&ytb[(size_t)(n0 + row) * CDIM + k * 32 + kq * 8];
            acc[0] = mfma16(Af, Bf[0][k], acc[0]);
            acc[1] = mfma16(Af, Bf[1][k], acc[1]);
        }
#pragma unroll
        for (int mm = 0; mm < 2; ++mm) {
            float t = fmaxf(fmaxf(acc[mm][0], acc[mm][1]), fmaxf(acc[mm][2], acc[mm][3]));
            float nm = fmaxf(mx[mm], t);
            float s = sm[mm] * __expf(mx[mm] - nm);
#pragma unroll
            for (int r = 0; r < 4; ++r) s += __expf(acc[mm][r] - nm);
            sm[mm] = s; mx[mm] = nm;
        }
    }
    // reduce across the 4 row-quad lane groups (same col m)
#pragma unroll
    for (int off = 16; off <= 32; off <<= 1) {
#pragma unroll
        for (int mm = 0; mm < 2; ++mm) {
            float omx = __shfl_xor(mx[mm], off);
            float osm = __shfl_xor(sm[mm], off);
            float nm = fmaxf(mx[mm], omx);
            sm[mm] = sm[mm] * __expf(mx[mm] - nm) + osm * __expf(omx - nm);
            mx[mm] = nm;
        }
    }
    __shared__ float smx[4][32], ssm[4][32];
    if (lane < 16) {
#pragma unroll
        for (int mm = 0; mm < 2; ++mm) {
            smx[wave][mm * 16 + lane] = mx[mm];
            ssm[wave][mm * 16 + lane] = sm[mm];
        }
    }
    __syncthreads();
    if (threadIdx.x < 32) {
        float M = -3.4e38f, S = 0.f;
#pragma unroll
        for (int w = 0; w < 4; ++w) {
            float m_ = smx[w][threadIdx.x], s_ = ssm[w][threadIdx.x];
            float nm = fmaxf(M, m_);
            S = S * __expf(M - nm) + s_ * __expf(m_ - nm);
            M = nm;
        }
        rowmax[(size_t)b * NDIM + m0 + threadIdx.x] = M;
        rowsum[(size_t)b * NDIM + m0 + threadIdx.x] = S;
    }
}

// ---------------------------------------------------------------------------
// K3 (MFMA): per m-tile (32 cols), sweep n in chunks of 64:
//   E tile via MFMA -> attn = exp(E-rmax)/rsum (fp16, into LDS attn_t[m][n])
//   -> PV MFMA: xr[c][m] += v[c][n] * attn[n][m]; colsum accumulated.
// Epilogue: xr *= 1/(1e-9+colsum). grid (N/32, B), 4 waves.
//   energy: wave w owns n-subtile w;  PV: wave w owns c-range [64w, 64w+64).
// ---------------------------------------------------------------------------
__global__ __launch_bounds__(256)
void k_attn_xr(const f16* __restrict__ yt, const f16* __restrict__ vh,
               const float* __restrict__ rowmax, const float* __restrict__ rowsum,
               float* __restrict__ xr)
{
    const int mt = blockIdx.x, b = blockIdx.y;
    const int wave = threadIdx.x >> 6, lane = threadIdx.x & 63;
    const int m0 = mt * 32;
    const int row = lane & 15, kq = lane >> 4;
    const f16* ytb = yt + (size_t)b * NDIM * CDIM;
    const f16* vhb = vh + (size_t)b * CDIM * NDIM;
    __shared__ __align__(16) f16 attn_t[32][72];   // [m][n], stride 72 halfs
    __shared__ float cred[4][32];
    __shared__ float cinv[32];
    // persistent energy B-frags (m side)
    f16x8 Bf[2][8];
#pragma unroll
    for (int mm = 0; mm < 2; ++mm)
#pragma unroll
        for (int k = 0; k < 8; ++k)
            Bf[mm][k] = *(const f16x8*)&ytb[(size_t)(m0 + mm * 16 + row) * CDIM + k * 32 + kq * 8];
    f32x4 xacc[4][2];
#pragma unroll
    for (int cc = 0; cc < 4; ++cc)
#pragma unroll
        for (int mm = 0; mm < 2; ++mm) xacc[cc][mm] = (f32x4){0.f, 0.f, 0.f, 0.f};
    float csum[2] = {0.f, 0.f};

    for (int it = 0; it < NDIM / 64; ++it) {
        const int n0 = it * 64;
        const int nb = n0 + wave * 16;          // this wave's energy n-subtile
        __syncthreads();                        // prev PV done reading attn_t
        f32x4 e[2] = {{0.f, 0.f, 0.f, 0.f}, {0.f, 0.f, 0.f, 0.f}};
#pragma unroll
        for (int k = 0; k < 8; ++k) {
            f16x8 Af = *(const f16x8*)&ytb[(size_t)(nb + row) * CDIM + k * 32 + kq * 8];
            e[0] = mfma16(Af, Bf[0][k], e[0]);
            e[1] = mfma16(Af, Bf[1][k], e[1]);
        }
        // attn = exp(E - rowmax[n]) / rowsum[n]; rows n = nb + kq*4 + r
        f32x4 rmx = *(const f32x4*)&rowmax[(size_t)b * NDIM + nb + kq * 4];
        f32x4 rsm = *(const f32x4*)&rowsum[(size_t)b * NDIM + nb + kq * 4];
#pragma unroll
        for (int mm = 0; mm < 2; ++mm) {
            f16x4 p;
#pragma unroll
            for (int r = 0; r < 4; ++r) {
                float a0 = __expf(e[mm][r] - rmx[r]) / rsm[r];
                csum[mm] += a0;
                p[r] = (f16)a0;
            }
            *(f16x4*)&attn_t[mm * 16 + row][wave * 16 + kq * 4] = p;
        }
        __syncthreads();                        // attn_t ready
        // PV: this wave owns c in [wave*64, wave*64+64)
#pragma unroll
        for (int ks = 0; ks < 2; ++ks) {
            f16x8 Bp[2];
#pragma unroll
            for (int mm = 0; mm < 2; ++mm)
                Bp[mm] = *(const f16x8*)&attn_t[mm * 16 + row][ks * 32 + kq * 8];
#pragma unroll
            for (int cc = 0; cc < 4; ++cc) {
                const int c = wave * 64 + cc * 16;
                f16x8 Ap = *(const f16x8*)&vhb[(size_t)(c + row) * NDIM + n0 + ks * 32 + kq * 8];
                xacc[cc][0] = mfma16(Ap, Bp[0], xacc[cc][0]);
                xacc[cc][1] = mfma16(Ap, Bp[1], xacc[cc][1]);
            }
        }
    }
    // colsum: reduce 4 row-quad lanes, then across waves
#pragma unroll
    for (int off = 16; off <= 32; off <<= 1)
#pragma unroll
        for (int mm = 0; mm < 2; ++mm) csum[mm] += __shfl_xor(csum[mm], off);
    if (lane < 16) {
#pragma unroll
        for (int mm = 0; mm < 2; ++mm) cred[wave][mm * 16 + lane] = csum[mm];
    }
    __syncthreads();
    if (threadIdx.x < 32) {
        float s = 0.f;
#pragma unroll
        for (int w = 0; w < 4; ++w) s += cred[w][threadIdx.x];
        cinv[threadIdx.x] = 1.f / (1e-9f + s);
    }
    __syncthreads();
#pragma unroll
    for (int mm = 0; mm < 2; ++mm) {
        float ci = cinv[mm * 16 + row];
#pragma unroll
        for (int cc = 0; cc < 4; ++cc) {
            const int c = wave * 64 + cc * 16 + kq * 4;
#pragma unroll
            for (int r = 0; r < 4; ++r)
                xr[((size_t)b * CDIM + c + r) * NDIM + m0 + mm * 16 + row] = xacc[cc][mm][r] * ci;
        }
    }
}

// ---------------------------------------------------------------------------
// K4a: t = Wt*(x - xr) + bt ; bn ; feat = x + relu(bn)   (fp32, unchanged)
// ---------------------------------------------------------------------------
__global__ __launch_bounds__(256)
void k_tbn(const float* __restrict__ x, const float* __restrict__ xr,
           const float* __restrict__ Wt, const float* __restrict__ bt,
           const float* __restrict__ gamma, const float* __restrict__ beta,
           float* __restrict__ feat)
{
    const int nt = blockIdx.x, ct = blockIdx.y, b = blockIdx.z;
    const int tid = threadIdx.x, tx = tid & 15, ty = tid >> 4;
    const int n0 = nt * 64, c0 = ct * 64;
    __shared__ float w_s[64][20], d_s[16][64];
    float acc[4][4] = {};
    const int wr = tid >> 2, wc = (tid & 3) * 4;
    const int sr = tid >> 4, sc = (tid & 15) * 4;
    for (int ck = 0; ck < CDIM; ck += 16) {
        *(float4*)&w_s[wr][wc] = *(const float4*)&Wt[(size_t)(c0 + wr) * CDIM + ck + wc];
        size_t doff = ((size_t)b * CDIM + ck + sr) * NDIM + n0 + sc;
        float4 xv = *(const float4*)&x[doff];
        float4 rv = *(const float4*)&xr[doff];
        *(float4*)&d_s[sr][sc] = make_float4(xv.x - rv.x, xv.y - rv.y, xv.z - rv.z, xv.w - rv.w);
        __syncthreads();
#pragma unroll
        for (int c4 = 0; c4 < 4; ++c4) {
            float4 w4[4];
#pragma unroll
            for (int i = 0; i < 4; ++i) w4[i] = *(const float4*)&w_s[ty * 4 + i][c4 * 4];
#pragma unroll
            for (int l = 0; l < 4; ++l) {
                float4 xl = *(const float4*)&d_s[c4 * 4 + l][tx * 4];
#pragma unroll
                for (int i = 0; i < 4; ++i) {
                    float wil = f4get(w4[i], l);
#pragma unroll
                    for (int j = 0; j < 4; ++j) acc[i][j] += wil * f4get(xl, j);
                }
            }
        }
        __syncthreads();
    }
    const float bnsc = 0.99999500003749968f; // 1/sqrt(1 + 1e-5)
#pragma unroll
    for (int i = 0; i < 4; ++i) {
        int co = c0 + ty * 4 + i;
        float g = gamma[co] * bnsc, be = beta[co], bb = bt[co];
        size_t off = ((size_t)b * CDIM + co) * NDIM + n0 + tx * 4;
        float4 xv = *(const float4*)&x[off];
        float4 o;
#pragma unroll
        for (int j = 0; j < 4; ++j)
            (&o.x)[j] = f4get(xv, j) + fmaxf((acc[i][j] + bb) * g + be, 0.f);
        *(float4*)&feat[off] = o;
    }
}

// ---------------------------------------------------------------------------
// K4b: query = Wproj*feat + bproj
// ---------------------------------------------------------------------------
__global__ __launch_bounds__(256)
void k_query(const float* __restrict__ feat, const float* __restrict__ Wp,
             const float* __restrict__ bp, float* __restrict__ query)
{
    __shared__ float wp_s[3 * CDIM];
    const int tid = threadIdx.x, b = blockIdx.y;
    for (int i = tid; i < 3 * CDIM; i += 256) wp_s[i] = Wp[i];
    __syncthreads();
    const int n = blockIdx.x * 256 + tid;
    float a0 = 0.f, a1 = 0.f, a2 = 0.f;
    const float* fb = feat + (size_t)b * CDIM * NDIM + n;
    for (int c = 0; c < CDIM; ++c) {
        float f = fb[(size_t)c * NDIM];
        a0 += wp_s[c] * f;
        a1 += wp_s[CDIM + c] * f;
        a2 += wp_s[2 * CDIM + c] * f;
    }
    query[((size_t)b * 3 + 0) * NDIM + n] = a0 + bp[0];
    query[((size_t)b * 3 + 1) * NDIM + n] = a1 + bp[1];
    query[((size_t)b * 3 + 2) * NDIM + n] = a2 + bp[2];
}

// ---------------------------------------------------------------------------
// K5: soft projection (unchanged)
// ---------------------------------------------------------------------------
__global__ __launch_bounds__(256)
void k_softproj(const float* __restrict__ pc, const float* __restrict__ query,
                const float* __restrict__ temp_p, float* __restrict__ out)
{
    __shared__ float px[MDIM], py[MDIM], pz[MDIM], p2[MDIM];
    const int tid = threadIdx.x, b = blockIdx.y;
    const float* pb = pc + (size_t)b * 3 * MDIM;
    for (int i = tid; i < MDIM; i += 256) {
        float a = pb[i], c = pb[MDIM + i], d = pb[2 * MDIM + i];
        px[i] = a; py[i] = c; pz[i] = d;
        p2[i] = a * a + c * c + d * d;
    }
    __syncthreads();
    const int n = blockIdx.x * 256 + tid;
    const float qx = query[((size_t)b * 3 + 0) * NDIM + n];
    const float qy = query[((size_t)b * 3 + 1) * NDIM + n];
    const float qz = query[((size_t)b * 3 + 2) * NDIM + n];
    const float q2 = qx * qx + qy * qy + qz * qz;
    float bd[KNN];
    int bi[KNN];
#pragma unroll
    for (int k = 0; k < KNN; ++k) { bd[k] = 3.4e38f; bi[k] = 0; }
    for (int m = 0; m < MDIM; ++m) {
        float d2 = q2 + p2[m] - 2.0f * (qx * px[m] + qy * py[m] + qz * pz[m]);
        if (d2 < bd[KNN - 1]) {
            bd[KNN - 1] = d2; bi[KNN - 1] = m;
#pragma unroll
            for (int k = KNN - 1; k > 0; --k) {
                if (bd[k] < bd[k - 1]) {
                    float td = bd[k]; bd[k] = bd[k - 1]; bd[k - 1] = td;
                    int ti = bi[k]; bi[k] = bi[k - 1]; bi[k - 1] = ti;
                }
            }
        }
    }
    const float temp = temp_p[0];
    const float sigma = fmaxf(temp * temp, 1e-4f) + 1e-8f;
    const float inv_sig = 1.0f / sigma;
    float gx[KNN], gy[KNN], gz[KNN], dist[KNN];
#pragma unroll
    for (int k = 0; k < KNN; ++k) {
        int m = bi[k];
        gx[k] = px[m]; gy[k] = py[m]; gz[k] = pz[m];
        float dx = gx[k] - qx, dy = gy[k] - qy, dz = gz[k] - qz;
        dist[k] = (dx * dx + dy * dy + dz * dz) * inv_sig;
    }
    float mn = dist[0];
#pragma unroll
    for (int k = 1; k < KNN; ++k) mn = fminf(mn, dist[k]);
    float wsum = 0.f, ox = 0.f, oy = 0.f, oz = 0.f;
#pragma unroll
    for (int k = 0; k < KNN; ++k) {
        float w = __expf(mn - dist[k]);
        wsum += w; ox += w * gx[k]; oy += w * gy[k]; oz += w * gz[k];
    }
    float invw = 1.0f / wsum;
    out[((size_t)b * 3 + 0) * NDIM + n] = ox * invw;
    out[((size_t)b * 3 + 1) * NDIM + n] = oy * invw;
    out[((size_t)b * 3 + 2) * NDIM + n] = oz * invw;
}

// ---------------------------------------------------------------------------
extern "C" void kernel_launch(void* const* d_in, const int* in_sizes, int n_in,
                              void* d_out, int out_size, void* d_ws, size_t ws_size,
                              hipStream_t stream)
{
    const float* x     = (const float*)d_in[0];
    const float* pc    = (const float*)d_in[1];
    const float* Wqk   = (const float*)d_in[2];
    const float* Wv    = (const float*)d_in[3];
    const float* bv    = (const float*)d_in[4];
    const float* Wt    = (const float*)d_in[5];
    const float* bt    = (const float*)d_in[6];
    const float* gamma = (const float*)d_in[7];
    const float* beta  = (const float*)d_in[8];
    const float* Wp    = (const float*)d_in[9];
    const float* bp    = (const float*)d_in[10];
    const float* temp  = (const float*)d_in[11];
    float* out = (float*)d_out;

    char* w = (char*)d_ws;
    f16*   yt     = (f16*)(w);                          // 8 MB  [b][n][c]
    f16*   vh     = (f16*)(w + (size_t)8  * 1024 * 1024);  // 8 MB  [b][c][n]
    float* xr     = (float*)(w + (size_t)16 * 1024 * 1024); // 16 MB
    float* feat   = (float*)(w + (size_t)32 * 1024 * 1024); // 16 MB
    float* rowmax = (float*)(w + (size_t)48 * 1024 * 1024); // 64 KB
    float* rowsum = rowmax + (size_t)BDIM * NDIM;
    float* query  = rowsum + (size_t)BDIM * NDIM;           // 192 KB

    k_qkv<<<dim3(NDIM / 64, CDIM / 64, BDIM), 256, 0, stream>>>(x, Wqk, Wv, bv, yt, vh);
    k_rowstats<<<dim3(NDIM / 32, BDIM), 256, 0, stream>>>(yt, rowmax, rowsum);
    k_attn_xr<<<dim3(NDIM / 32, BDIM), 256, 0, stream>>>(yt, vh, rowmax, rowsum, xr);
    k_tbn<<<dim3(NDIM / 64, CDIM / 64, BDIM), 256, 0, stream>>>(x, xr, Wt, bt, gamma, beta, feat);
    k_query<<<dim3(NDIM / 256, BDIM), 256, 0, stream>>>(feat, Wp, bp, query);
    k_softproj<<<dim3(NDIM / 256, BDIM), 256, 0, stream>>>(pc, query, temp, out);
}

// Round 3
// 690.826 us; speedup vs baseline: 3.0326x; 1.6145x over previous
//
#include <hip/hip_runtime.h>
#include <math.h>

#define BDIM 8
#define CDIM 256
#define NDIM 2048
#define MDIM 4096
#define KNN 10

typedef _Float16 f16;
typedef f16  f16x8 __attribute__((ext_vector_type(8)));
typedef f16  f16x4 __attribute__((ext_vector_type(4)));
typedef float f32x4 __attribute__((ext_vector_type(4)));

__device__ __forceinline__ float f4get(const float4& v, int i) { return (&v.x)[i]; }

__device__ __forceinline__ f32x4 mfma16(f16x8 a, f16x8 b, f32x4 c) {
    return __builtin_amdgcn_mfma_f32_16x16x32_f16(a, b, c, 0, 0, 0);
}

// ---------------------------------------------------------------------------
// K1: y = Wqk*x ; v = Wv*x + bv  (fp32 vector GEMM; epilogue emits fp16)
// outputs: yt[b][n][c] fp16 (transposed), vh[b][c][n] fp16
// ---------------------------------------------------------------------------
__global__ __launch_bounds__(256)
void k_qkv(const float* __restrict__ x, const float* __restrict__ Wqk,
           const float* __restrict__ Wv, const float* __restrict__ bv,
           f16* __restrict__ yt, f16* __restrict__ vh)
{
    const int nt = blockIdx.x, ct = blockIdx.y, b = blockIdx.z;
    const int tid = threadIdx.x, tx = tid & 15, ty = tid >> 4;
    const int n0 = nt * 64, c0 = ct * 64;
    __shared__ float wq_s[64][20], wv_s[64][20], x_s[16][64];
    float accy[4][4] = {}, accv[4][4] = {};
    const int wr = tid >> 2, wc = (tid & 3) * 4;
    const int sr = tid >> 4, sc = (tid & 15) * 4;
    for (int ck = 0; ck < CDIM; ck += 16) {
        *(float4*)&wq_s[wr][wc] = *(const float4*)&Wqk[(size_t)(c0 + wr) * CDIM + ck + wc];
        *(float4*)&wv_s[wr][wc] = *(const float4*)&Wv[(size_t)(c0 + wr) * CDIM + ck + wc];
        *(float4*)&x_s[sr][sc] = *(const float4*)&x[((size_t)b * CDIM + ck + sr) * NDIM + n0 + sc];
        __syncthreads();
#pragma unroll
        for (int c4 = 0; c4 < 4; ++c4) {
            float4 wq4[4], wv4[4];
#pragma unroll
            for (int i = 0; i < 4; ++i) {
                wq4[i] = *(const float4*)&wq_s[ty * 4 + i][c4 * 4];
                wv4[i] = *(const float4*)&wv_s[ty * 4 + i][c4 * 4];
            }
#pragma unroll
            for (int l = 0; l < 4; ++l) {
                float4 xl = *(const float4*)&x_s[c4 * 4 + l][tx * 4];
#pragma unroll
                for (int i = 0; i < 4; ++i) {
                    float wq_il = f4get(wq4[i], l), wv_il = f4get(wv4[i], l);
#pragma unroll
                    for (int j = 0; j < 4; ++j) {
                        accy[i][j] += wq_il * f4get(xl, j);
                        accv[i][j] += wv_il * f4get(xl, j);
                    }
                }
            }
        }
        __syncthreads();
    }
#pragma unroll
    for (int j = 0; j < 4; ++j) {
        f16x4 p;
#pragma unroll
        for (int i = 0; i < 4; ++i) p[i] = (f16)accy[i][j];
        *(f16x4*)&yt[((size_t)b * NDIM + n0 + tx * 4 + j) * CDIM + c0 + ty * 4] = p;
    }
#pragma unroll
    for (int i = 0; i < 4; ++i) {
        float bvv = bv[c0 + ty * 4 + i];
        f16x4 p;
#pragma unroll
        for (int j = 0; j < 4; ++j) p[j] = (f16)(accv[i][j] + bvv);
        *(f16x4*)&vh[((size_t)b * CDIM + c0 + ty * 4 + i) * NDIM + n0 + tx * 4] = p;
    }
}

// ---------------------------------------------------------------------------
// K2 (MFMA): row softmax stats of E = Y^T Y (symmetry-exploiting)
// ---------------------------------------------------------------------------
__global__ __launch_bounds__(256)
void k_rowstats(const f16* __restrict__ yt, float* __restrict__ rowmax,
                float* __restrict__ rowsum)
{
    const int mt = blockIdx.x, b = blockIdx.y;
    const int wave = threadIdx.x >> 6, lane = threadIdx.x & 63;
    const int m0 = mt * 32;
    const int row = lane & 15, kq = lane >> 4;
    const f16* ytb = yt + (size_t)b * NDIM * CDIM;
    f16x8 Bf[2][8];
#pragma unroll
    for (int mm = 0; mm < 2; ++mm)
#pragma unroll
        for (int k = 0; k < 8; ++k)
            Bf[mm][k] = *(const f16x8*)&ytb[(size_t)(m0 + mm * 16 + row) * CDIM + k * 32 + kq * 8];
    float mx[2] = {-3.4e38f, -3.4e38f}, sm[2] = {0.f, 0.f};
    for (int it = wave; it < NDIM / 16; it += 4) {
        const int n0 = it * 16;
        f32x4 acc[2] = {{0.f, 0.f, 0.f, 0.f}, {0.f, 0.f, 0.f, 0.f}};
#pragma unroll
        for (int k = 0; k < 8; ++k) {
            f16x8 Af = *(const f16x8*)&ytb[(size_t)(n0 + row) * CDIM + k * 32 + kq * 8];
            acc[0] = mfma16(Af, Bf[0][k], acc[0]);
            acc[1] = mfma16(Af, Bf[1][k], acc[1]);
        }
#pragma unroll
        for (int mm = 0; mm < 2; ++mm) {
            float t = fmaxf(fmaxf(acc[mm][0], acc[mm][1]), fmaxf(acc[mm][2], acc[mm][3]));
            float nm = fmaxf(mx[mm], t);
            float s = sm[mm] * __expf(mx[mm] - nm);
#pragma unroll
            for (int r = 0; r < 4; ++r) s += __expf(acc[mm][r] - nm);
            sm[mm] = s; mx[mm] = nm;
        }
    }
#pragma unroll
    for (int off = 16; off <= 32; off <<= 1) {
#pragma unroll
        for (int mm = 0; mm < 2; ++mm) {
            float omx = __shfl_xor(mx[mm], off);
            float osm = __shfl_xor(sm[mm], off);
            float nm = fmaxf(mx[mm], omx);
            sm[mm] = sm[mm] * __expf(mx[mm] - nm) + osm * __expf(omx - nm);
            mx[mm] = nm;
        }
    }
    __shared__ float smx[4][32], ssm[4][32];
    if (lane < 16) {
#pragma unroll
        for (int mm = 0; mm < 2; ++mm) {
            smx[wave][mm * 16 + lane] = mx[mm];
            ssm[wave][mm * 16 + lane] = sm[mm];
        }
    }
    __syncthreads();
    if (threadIdx.x < 32) {
        float M = -3.4e38f, S = 0.f;
#pragma unroll
        for (int w = 0; w < 4; ++w) {
            float m_ = smx[w][threadIdx.x], s_ = ssm[w][threadIdx.x];
            float nm = fmaxf(M, m_);
            S = S * __expf(M - nm) + s_ * __expf(m_ - nm);
            M = nm;
        }
        rowmax[(size_t)b * NDIM + m0 + threadIdx.x] = M;
        rowsum[(size_t)b * NDIM + m0 + threadIdx.x] = S;
    }
}

// ---------------------------------------------------------------------------
// K3 (MFMA): energy tile -> attn(fp16, LDS) -> PV; colsum renorm epilogue
// ---------------------------------------------------------------------------
__global__ __launch_bounds__(256)
void k_attn_xr(const f16* __restrict__ yt, const f16* __restrict__ vh,
               const float* __restrict__ rowmax, const float* __restrict__ rowsum,
               float* __restrict__ xr)
{
    const int mt = blockIdx.x, b = blockIdx.y;
    const int wave = threadIdx.x >> 6, lane = threadIdx.x & 63;
    const int m0 = mt * 32;
    const int row = lane & 15, kq = lane >> 4;
    const f16* ytb = yt + (size_t)b * NDIM * CDIM;
    const f16* vhb = vh + (size_t)b * CDIM * NDIM;
    __shared__ __align__(16) f16 attn_t[32][72];
    __shared__ float cred[4][32];
    __shared__ float cinv[32];
    f16x8 Bf[2][8];
#pragma unroll
    for (int mm = 0; mm < 2; ++mm)
#pragma unroll
        for (int k = 0; k < 8; ++k)
            Bf[mm][k] = *(const f16x8*)&ytb[(size_t)(m0 + mm * 16 + row) * CDIM + k * 32 + kq * 8];
    f32x4 xacc[4][2];
#pragma unroll
    for (int cc = 0; cc < 4; ++cc)
#pragma unroll
        for (int mm = 0; mm < 2; ++mm) xacc[cc][mm] = (f32x4){0.f, 0.f, 0.f, 0.f};
    float csum[2] = {0.f, 0.f};

    for (int it = 0; it < NDIM / 64; ++it) {
        const int n0 = it * 64;
        const int nb = n0 + wave * 16;
        __syncthreads();
        f32x4 e[2] = {{0.f, 0.f, 0.f, 0.f}, {0.f, 0.f, 0.f, 0.f}};
#pragma unroll
        for (int k = 0; k < 8; ++k) {
            f16x8 Af = *(const f16x8*)&ytb[(size_t)(nb + row) * CDIM + k * 32 + kq * 8];
            e[0] = mfma16(Af, Bf[0][k], e[0]);
            e[1] = mfma16(Af, Bf[1][k], e[1]);
        }
        f32x4 rmx = *(const f32x4*)&rowmax[(size_t)b * NDIM + nb + kq * 4];
        f32x4 rsm = *(const f32x4*)&rowsum[(size_t)b * NDIM + nb + kq * 4];
#pragma unroll
        for (int mm = 0; mm < 2; ++mm) {
            f16x4 p;
#pragma unroll
            for (int r = 0; r < 4; ++r) {
                float a0 = __expf(e[mm][r] - rmx[r]) / rsm[r];
                csum[mm] += a0;
                p[r] = (f16)a0;
            }
            *(f16x4*)&attn_t[mm * 16 + row][wave * 16 + kq * 4] = p;
        }
        __syncthreads();
#pragma unroll
        for (int ks = 0; ks < 2; ++ks) {
            f16x8 Bp[2];
#pragma unroll
            for (int mm = 0; mm < 2; ++mm)
                Bp[mm] = *(const f16x8*)&attn_t[mm * 16 + row][ks * 32 + kq * 8];
#pragma unroll
            for (int cc = 0; cc < 4; ++cc) {
                const int c = wave * 64 + cc * 16;
                f16x8 Ap = *(const f16x8*)&vhb[(size_t)(c + row) * NDIM + n0 + ks * 32 + kq * 8];
                xacc[cc][0] = mfma16(Ap, Bp[0], xacc[cc][0]);
                xacc[cc][1] = mfma16(Ap, Bp[1], xacc[cc][1]);
            }
        }
    }
#pragma unroll
    for (int off = 16; off <= 32; off <<= 1)
#pragma unroll
        for (int mm = 0; mm < 2; ++mm) csum[mm] += __shfl_xor(csum[mm], off);
    if (lane < 16) {
#pragma unroll
        for (int mm = 0; mm < 2; ++mm) cred[wave][mm * 16 + lane] = csum[mm];
    }
    __syncthreads();
    if (threadIdx.x < 32) {
        float s = 0.f;
#pragma unroll
        for (int w = 0; w < 4; ++w) s += cred[w][threadIdx.x];
        cinv[threadIdx.x] = 1.f / (1e-9f + s);
    }
    __syncthreads();
#pragma unroll
    for (int mm = 0; mm < 2; ++mm) {
        float ci = cinv[mm * 16 + row];
#pragma unroll
        for (int cc = 0; cc < 4; ++cc) {
            const int c = wave * 64 + cc * 16 + kq * 4;
#pragma unroll
            for (int r = 0; r < 4; ++r)
                xr[((size_t)b * CDIM + c + r) * NDIM + m0 + mm * 16 + row] = xacc[cc][mm][r] * ci;
        }
    }
}

// ---------------------------------------------------------------------------
// K4a: t = Wt*(x - xr) + bt ; bn ; feat = x + relu(bn)
// ---------------------------------------------------------------------------
__global__ __launch_bounds__(256)
void k_tbn(const float* __restrict__ x, const float* __restrict__ xr,
           const float* __restrict__ Wt, const float* __restrict__ bt,
           const float* __restrict__ gamma, const float* __restrict__ beta,
           float* __restrict__ feat)
{
    const int nt = blockIdx.x, ct = blockIdx.y, b = blockIdx.z;
    const int tid = threadIdx.x, tx = tid & 15, ty = tid >> 4;
    const int n0 = nt * 64, c0 = ct * 64;
    __shared__ float w_s[64][20], d_s[16][64];
    float acc[4][4] = {};
    const int wr = tid >> 2, wc = (tid & 3) * 4;
    const int sr = tid >> 4, sc = (tid & 15) * 4;
    for (int ck = 0; ck < CDIM; ck += 16) {
        *(float4*)&w_s[wr][wc] = *(const float4*)&Wt[(size_t)(c0 + wr) * CDIM + ck + wc];
        size_t doff = ((size_t)b * CDIM + ck + sr) * NDIM + n0 + sc;
        float4 xv = *(const float4*)&x[doff];
        float4 rv = *(const float4*)&xr[doff];
        *(float4*)&d_s[sr][sc] = make_float4(xv.x - rv.x, xv.y - rv.y, xv.z - rv.z, xv.w - rv.w);
        __syncthreads();
#pragma unroll
        for (int c4 = 0; c4 < 4; ++c4) {
            float4 w4[4];
#pragma unroll
            for (int i = 0; i < 4; ++i) w4[i] = *(const float4*)&w_s[ty * 4 + i][c4 * 4];
#pragma unroll
            for (int l = 0; l < 4; ++l) {
                float4 xl = *(const float4*)&d_s[c4 * 4 + l][tx * 4];
#pragma unroll
                for (int i = 0; i < 4; ++i) {
                    float wil = f4get(w4[i], l);
#pragma unroll
                    for (int j = 0; j < 4; ++j) acc[i][j] += wil * f4get(xl, j);
                }
            }
        }
        __syncthreads();
    }
    const float bnsc = 0.99999500003749968f; // 1/sqrt(1 + 1e-5)
#pragma unroll
    for (int i = 0; i < 4; ++i) {
        int co = c0 + ty * 4 + i;
        float g = gamma[co] * bnsc, be = beta[co], bb = bt[co];
        size_t off = ((size_t)b * CDIM + co) * NDIM + n0 + tx * 4;
        float4 xv = *(const float4*)&x[off];
        float4 o;
#pragma unroll
        for (int j = 0; j < 4; ++j)
            (&o.x)[j] = f4get(xv, j) + fmaxf((acc[i][j] + bb) * g + be, 0.f);
        *(float4*)&feat[off] = o;
    }
}

// ---------------------------------------------------------------------------
// K4b: query = Wproj*feat + bproj
// ---------------------------------------------------------------------------
__global__ __launch_bounds__(256)
void k_query(const float* __restrict__ feat, const float* __restrict__ Wp,
             const float* __restrict__ bp, float* __restrict__ query)
{
    __shared__ float wp_s[3 * CDIM];
    const int tid = threadIdx.x, b = blockIdx.y;
    for (int i = tid; i < 3 * CDIM; i += 256) wp_s[i] = Wp[i];
    __syncthreads();
    const int n = blockIdx.x * 256 + tid;
    float a0 = 0.f, a1 = 0.f, a2 = 0.f;
    const float* fb = feat + (size_t)b * CDIM * NDIM + n;
    for (int c = 0; c < CDIM; ++c) {
        float f = fb[(size_t)c * NDIM];
        a0 += wp_s[c] * f;
        a1 += wp_s[CDIM + c] * f;
        a2 += wp_s[2 * CDIM + c] * f;
    }
    query[((size_t)b * 3 + 0) * NDIM + n] = a0 + bp[0];
    query[((size_t)b * 3 + 1) * NDIM + n] = a1 + bp[1];
    query[((size_t)b * 3 + 2) * NDIM + n] = a2 + bp[2];
}

// ---------------------------------------------------------------------------
// K5 v2: soft projection — 8 lanes per query, interleaved scan + tournament
// merge. grid (N/32, B), 256 thr; LDS = pt[4096] float4 (x,y,z,|p|^2) 64 KB.
// ---------------------------------------------------------------------------
__global__ __launch_bounds__(256)
void k_softproj(const float* __restrict__ pc, const float* __restrict__ query,
                const float* __restrict__ temp_p, float* __restrict__ out)
{
    __shared__ __align__(16) float4 pt[MDIM];          // 64 KB
    const int tid = threadIdx.x, b = blockIdx.y;
    const float* pb = pc + (size_t)b * 3 * MDIM;
    for (int i = tid; i < MDIM; i += 256) {
        float a = pb[i], c = pb[MDIM + i], d = pb[2 * MDIM + i];
        pt[i] = make_float4(a, c, d, a * a + c * c + d * d);
    }
    __syncthreads();
    const int qloc = tid >> 3;          // 0..31 query within block
    const int j = tid & 7;              // lane within query group
    const int n = blockIdx.x * 32 + qloc;
    const float qx = query[((size_t)b * 3 + 0) * NDIM + n];
    const float qy = query[((size_t)b * 3 + 1) * NDIM + n];
    const float qz = query[((size_t)b * 3 + 2) * NDIM + n];
    const float q2 = qx * qx + qy * qy + qz * qz;

    float bd[KNN];
    int bi[KNN];
#pragma unroll
    for (int k = 0; k < KNN; ++k) { bd[k] = 3.4e38f; bi[k] = 0x7fffffff; }
    // each lane scans m = t*8 + j, t = 0..511
    for (int t = 0; t < MDIM / 8; ++t) {
        const int m = t * 8 + j;
        float4 p = pt[m];
        float d2 = q2 + p.w - 2.0f * (qx * p.x + qy * p.y + qz * p.z);
        if (d2 < bd[KNN - 1]) {
            bd[KNN - 1] = d2; bi[KNN - 1] = m;
#pragma unroll
            for (int k = KNN - 1; k > 0; --k) {
                bool sw = bd[k] < bd[k - 1];
                float td = sw ? bd[k - 1] : bd[k];
                bd[k - 1] = sw ? bd[k] : bd[k - 1];
                bd[k] = td;
                int ti = sw ? bi[k - 1] : bi[k];
                bi[k - 1] = sw ? bi[k] : bi[k - 1];
                bi[k] = ti;
            }
        }
    }
    // tournament merge of 8 sorted lists -> winner indices (in all 8 lanes)
    int wi[KNN];
#pragma unroll
    for (int k = 0; k < KNN; ++k) {
        float d = bd[0];
        int idx = bi[0];
#pragma unroll
        for (int off = 1; off <= 4; off <<= 1) {
            float od = __shfl_xor(d, off);
            int oi = __shfl_xor(idx, off);
            if (od < d || (od == d && oi < idx)) { d = od; idx = oi; }
        }
        wi[k] = idx;
        bool won = (bd[0] == d) && (bi[0] == idx);
#pragma unroll
        for (int s = 0; s < KNN - 1; ++s) {
            bd[s] = won ? bd[s + 1] : bd[s];
            bi[s] = won ? bi[s + 1] : bi[s];
        }
        if (won) { bd[KNN - 1] = 3.4e38f; bi[KNN - 1] = 0x7fffffff; }
    }
    // softmax-weighted sum over winners (redundant on 8 lanes; lane 0 writes)
    const float temp = temp_p[0];
    const float sigma = fmaxf(temp * temp, 1e-4f) + 1e-8f;
    const float inv_sig = 1.0f / sigma;
    float gx[KNN], gy[KNN], gz[KNN], dist[KNN];
#pragma unroll
    for (int k = 0; k < KNN; ++k) {
        float4 p = pt[wi[k]];
        gx[k] = p.x; gy[k] = p.y; gz[k] = p.z;
        float dx = p.x - qx, dy = p.y - qy, dz = p.z - qz;
        dist[k] = (dx * dx + dy * dy + dz * dz) * inv_sig;
    }
    float mn = dist[0];
#pragma unroll
    for (int k = 1; k < KNN; ++k) mn = fminf(mn, dist[k]);
    float wsum = 0.f, ox = 0.f, oy = 0.f, oz = 0.f;
#pragma unroll
    for (int k = 0; k < KNN; ++k) {
        float w = __expf(mn - dist[k]);
        wsum += w; ox += w * gx[k]; oy += w * gy[k]; oz += w * gz[k];
    }
    if (j == 0) {
        float invw = 1.0f / wsum;
        out[((size_t)b * 3 + 0) * NDIM + n] = ox * invw;
        out[((size_t)b * 3 + 1) * NDIM + n] = oy * invw;
        out[((size_t)b * 3 + 2) * NDIM + n] = oz * invw;
    }
}

// ---------------------------------------------------------------------------
extern "C" void kernel_launch(void* const* d_in, const int* in_sizes, int n_in,
                              void* d_out, int out_size, void* d_ws, size_t ws_size,
                              hipStream_t stream)
{
    const float* x     = (const float*)d_in[0];
    const float* pc    = (const float*)d_in[1];
    const float* Wqk   = (const float*)d_in[2];
    const float* Wv    = (const float*)d_in[3];
    const float* bv    = (const float*)d_in[4];
    const float* Wt    = (const float*)d_in[5];
    const float* bt    = (const float*)d_in[6];
    const float* gamma = (const float*)d_in[7];
    const float* beta  = (const float*)d_in[8];
    const float* Wp    = (const float*)d_in[9];
    const float* bp    = (const float*)d_in[10];
    const float* temp  = (const float*)d_in[11];
    float* out = (float*)d_out;

    char* w = (char*)d_ws;
    f16*   yt     = (f16*)(w);                               // 8 MB  [b][n][c]
    f16*   vh     = (f16*)(w + (size_t)8  * 1024 * 1024);    // 8 MB  [b][c][n]
    float* xr     = (float*)(w + (size_t)16 * 1024 * 1024);  // 16 MB
    float* feat   = (float*)(w + (size_t)32 * 1024 * 1024);  // 16 MB
    float* rowmax = (float*)(w + (size_t)48 * 1024 * 1024);  // 64 KB
    float* rowsum = rowmax + (size_t)BDIM * NDIM;
    float* query  = rowsum + (size_t)BDIM * NDIM;            // 192 KB

    k_qkv<<<dim3(NDIM / 64, CDIM / 64, BDIM), 256, 0, stream>>>(x, Wqk, Wv, bv, yt, vh);
    k_rowstats<<<dim3(NDIM / 32, BDIM), 256, 0, stream>>>(yt, rowmax, rowsum);
    k_attn_xr<<<dim3(NDIM / 32, BDIM), 256, 0, stream>>>(yt, vh, rowmax, rowsum, xr);
    k_tbn<<<dim3(NDIM / 64, CDIM / 64, BDIM), 256, 0, stream>>>(x, xr, Wt, bt, gamma, beta, feat);
    k_query<<<dim3(NDIM / 256, BDIM), 256, 0, stream>>>(feat, Wp, bp, query);
    k_softproj<<<dim3(NDIM / 32, BDIM), 256, 0, stream>>>(pc, query, temp, out);
}

// Round 4
// 475.527 us; speedup vs baseline: 4.4057x; 1.4528x over previous
//
#include <hip/hip_runtime.h>
#include <math.h>

#define BDIM 8
#define CDIM 256
#define NDIM 2048
#define MDIM 4096
#define KNN 10

typedef _Float16 f16;
typedef f16  f16x8 __attribute__((ext_vector_type(8)));
typedef f16  f16x4 __attribute__((ext_vector_type(4)));
typedef float f32x4 __attribute__((ext_vector_type(4)));

__device__ __forceinline__ f32x4 mfma16(f16x8 a, f16x8 b, f32x4 c) {
    return __builtin_amdgcn_mfma_f32_16x16x32_f16(a, b, c, 0, 0, 0);
}

// ---------------------------------------------------------------------------
// P1: weights -> fp16 (grid 256 x 256 covers 65536 elements of each W)
// ---------------------------------------------------------------------------
__global__ __launch_bounds__(256)
void k_prep_w(const float* __restrict__ Wqk, const float* __restrict__ Wv,
              const float* __restrict__ Wt,
              f16* __restrict__ wqh, f16* __restrict__ wvh, f16* __restrict__ wth)
{
    int i = blockIdx.x * 256 + threadIdx.x;
    wqh[i] = (f16)Wqk[i];
    wvh[i] = (f16)Wv[i];
    wth[i] = (f16)Wt[i];
}

// ---------------------------------------------------------------------------
// P2: pt4[b][m] = (x, y, z, |p|^2)   (grid 128 x 256 = B*M)
// ---------------------------------------------------------------------------
__global__ __launch_bounds__(256)
void k_prep_pt(const float* __restrict__ pc, float4* __restrict__ pt4)
{
    int i = blockIdx.x * 256 + threadIdx.x;
    int b = i >> 12, m = i & (MDIM - 1);
    const float* pb = pc + (size_t)b * 3 * MDIM;
    float a = pb[m], c = pb[MDIM + m], d = pb[2 * MDIM + m];
    pt4[i] = make_float4(a, c, d, a * a + c * c + d * d);
}

// ---------------------------------------------------------------------------
// P3: xt[b][n][c] = fp16(x[b][c][n])  via LDS tile transpose
// grid (N/64, C/64, B), 256 thr
// ---------------------------------------------------------------------------
__global__ __launch_bounds__(256)
void k_xt(const float* __restrict__ x, f16* __restrict__ xt)
{
    __shared__ float ls[64][68];
    const int nt = blockIdx.x, ct = blockIdx.y, b = blockIdx.z;
    const int tid = threadIdx.x;
    const int n0 = nt * 64, c0 = ct * 64;
    const int cl = tid >> 4, n4 = (tid & 15) * 4;
#pragma unroll
    for (int q = 0; q < 4; ++q) {
        int c = q * 16 + cl;
        *(float4*)&ls[c][n4] = *(const float4*)&x[((size_t)b * CDIM + c0 + c) * NDIM + n0 + n4];
    }
    __syncthreads();
    const int c4 = (tid & 15) * 4;
#pragma unroll
    for (int q = 0; q < 4; ++q) {
        int n = q * 16 + cl;
        f16x4 p;
#pragma unroll
        for (int r = 0; r < 4; ++r) p[r] = (f16)ls[c4 + r][n];
        *(f16x4*)&xt[((size_t)b * NDIM + n0 + n) * CDIM + c0 + c4] = p;
    }
}

// ---------------------------------------------------------------------------
// K1 (MFMA): y = Wqk*x ; v = Wv*x + bv.  A = W[o][c], B = xt[n][c].
// outputs yt[b][n][c] fp16, vh[b][c][n] fp16. grid (N/64, C/64, B), 4 waves.
// ---------------------------------------------------------------------------
__global__ __launch_bounds__(256)
void k_qkv(const f16* __restrict__ xt, const f16* __restrict__ wqh,
           const f16* __restrict__ wvh, const float* __restrict__ bv,
           f16* __restrict__ yt, f16* __restrict__ vh)
{
    const int nt = blockIdx.x, ct = blockIdx.y, b = blockIdx.z;
    const int wave = threadIdx.x >> 6, lane = threadIdx.x & 63;
    const int row = lane & 15, kq = lane >> 4;
    const int n0 = nt * 64, o0 = ct * 64 + wave * 16;
    const f16* xb = xt + (size_t)b * NDIM * CDIM;
    f32x4 accy[4], accv[4];
#pragma unroll
    for (int j = 0; j < 4; ++j) {
        accy[j] = (f32x4){0.f, 0.f, 0.f, 0.f};
        accv[j] = (f32x4){0.f, 0.f, 0.f, 0.f};
    }
#pragma unroll
    for (int k = 0; k < 8; ++k) {
        f16x8 Aq = *(const f16x8*)&wqh[(size_t)(o0 + row) * CDIM + k * 32 + kq * 8];
        f16x8 Av = *(const f16x8*)&wvh[(size_t)(o0 + row) * CDIM + k * 32 + kq * 8];
#pragma unroll
        for (int j = 0; j < 4; ++j) {
            f16x8 Bx = *(const f16x8*)&xb[(size_t)(n0 + j * 16 + row) * CDIM + k * 32 + kq * 8];
            accy[j] = mfma16(Aq, Bx, accy[j]);
            accv[j] = mfma16(Av, Bx, accv[j]);
        }
    }
#pragma unroll
    for (int j = 0; j < 4; ++j) {
        const int n = n0 + j * 16 + row;
        f16x4 p;
#pragma unroll
        for (int r = 0; r < 4; ++r) p[r] = (f16)accy[j][r];
        *(f16x4*)&yt[((size_t)b * NDIM + n) * CDIM + o0 + kq * 4] = p;
#pragma unroll
        for (int r = 0; r < 4; ++r) {
            const int o = o0 + kq * 4 + r;
            vh[((size_t)b * CDIM + o) * NDIM + n] = (f16)(accv[j][r] + bv[o]);
        }
    }
}

// ---------------------------------------------------------------------------
// K2 (MFMA): row softmax stats of E = Y^T Y (symmetry-exploiting)
// ---------------------------------------------------------------------------
__global__ __launch_bounds__(256)
void k_rowstats(const f16* __restrict__ yt, float* __restrict__ rowmax,
                float* __restrict__ rowsum)
{
    const int mt = blockIdx.x, b = blockIdx.y;
    const int wave = threadIdx.x >> 6, lane = threadIdx.x & 63;
    const int m0 = mt * 32;
    const int row = lane & 15, kq = lane >> 4;
    const f16* ytb = yt + (size_t)b * NDIM * CDIM;
    f16x8 Bf[2][8];
#pragma unroll
    for (int mm = 0; mm < 2; ++mm)
#pragma unroll
        for (int k = 0; k < 8; ++k)
            Bf[mm][k] = *(const f16x8*)&ytb[(size_t)(m0 + mm * 16 + row) * CDIM + k * 32 + kq * 8];
    float mx[2] = {-3.4e38f, -3.4e38f}, sm[2] = {0.f, 0.f};
    for (int it = wave; it < NDIM / 16; it += 4) {
        const int n0 = it * 16;
        f32x4 acc[2] = {{0.f, 0.f, 0.f, 0.f}, {0.f, 0.f, 0.f, 0.f}};
#pragma unroll
        for (int k = 0; k < 8; ++k) {
            f16x8 Af = *(const f16x8*)&ytb[(size_t)(n0 + row) * CDIM + k * 32 + kq * 8];
            acc[0] = mfma16(Af, Bf[0][k], acc[0]);
            acc[1] = mfma16(Af, Bf[1][k], acc[1]);
        }
#pragma unroll
        for (int mm = 0; mm < 2; ++mm) {
            float t = fmaxf(fmaxf(acc[mm][0], acc[mm][1]), fmaxf(acc[mm][2], acc[mm][3]));
            float nm = fmaxf(mx[mm], t);
            float s = sm[mm] * __expf(mx[mm] - nm);
#pragma unroll
            for (int r = 0; r < 4; ++r) s += __expf(acc[mm][r] - nm);
            sm[mm] = s; mx[mm] = nm;
        }
    }
#pragma unroll
    for (int off = 16; off <= 32; off <<= 1) {
#pragma unroll
        for (int mm = 0; mm < 2; ++mm) {
            float omx = __shfl_xor(mx[mm], off);
            float osm = __shfl_xor(sm[mm], off);
            float nm = fmaxf(mx[mm], omx);
            sm[mm] = sm[mm] * __expf(mx[mm] - nm) + osm * __expf(omx - nm);
            mx[mm] = nm;
        }
    }
    __shared__ float smx[4][32], ssm[4][32];
    if (lane < 16) {
#pragma unroll
        for (int mm = 0; mm < 2; ++mm) {
            smx[wave][mm * 16 + lane] = mx[mm];
            ssm[wave][mm * 16 + lane] = sm[mm];
        }
    }
    __syncthreads();
    if (threadIdx.x < 32) {
        float M = -3.4e38f, S = 0.f;
#pragma unroll
        for (int w = 0; w < 4; ++w) {
            float m_ = smx[w][threadIdx.x], s_ = ssm[w][threadIdx.x];
            float nm = fmaxf(M, m_);
            S = S * __expf(M - nm) + s_ * __expf(m_ - nm);
            M = nm;
        }
        rowmax[(size_t)b * NDIM + m0 + threadIdx.x] = M;
        rowsum[(size_t)b * NDIM + m0 + threadIdx.x] = S;
    }
}

// ---------------------------------------------------------------------------
// K3 (MFMA): energy -> attn(fp16, LDS) -> PV; epilogue emits
// dh[b][n][c] = fp16(x - xr) directly (renormalized by colsum).
// ---------------------------------------------------------------------------
__global__ __launch_bounds__(256)
void k_attn_xr(const f16* __restrict__ yt, const f16* __restrict__ vh,
               const float* __restrict__ rowmax, const float* __restrict__ rowsum,
               const float* __restrict__ x, f16* __restrict__ dh)
{
    const int mt = blockIdx.x, b = blockIdx.y;
    const int wave = threadIdx.x >> 6, lane = threadIdx.x & 63;
    const int m0 = mt * 32;
    const int row = lane & 15, kq = lane >> 4;
    const f16* ytb = yt + (size_t)b * NDIM * CDIM;
    const f16* vhb = vh + (size_t)b * CDIM * NDIM;
    __shared__ __align__(16) f16 attn_t[32][72];
    __shared__ float cred[4][32];
    __shared__ float cinv[32];
    f16x8 Bf[2][8];
#pragma unroll
    for (int mm = 0; mm < 2; ++mm)
#pragma unroll
        for (int k = 0; k < 8; ++k)
            Bf[mm][k] = *(const f16x8*)&ytb[(size_t)(m0 + mm * 16 + row) * CDIM + k * 32 + kq * 8];
    f32x4 xacc[4][2];
#pragma unroll
    for (int cc = 0; cc < 4; ++cc)
#pragma unroll
        for (int mm = 0; mm < 2; ++mm) xacc[cc][mm] = (f32x4){0.f, 0.f, 0.f, 0.f};
    float csum[2] = {0.f, 0.f};

    for (int it = 0; it < NDIM / 64; ++it) {
        const int n0 = it * 64;
        const int nb = n0 + wave * 16;
        __syncthreads();
        f32x4 e[2] = {{0.f, 0.f, 0.f, 0.f}, {0.f, 0.f, 0.f, 0.f}};
#pragma unroll
        for (int k = 0; k < 8; ++k) {
            f16x8 Af = *(const f16x8*)&ytb[(size_t)(nb + row) * CDIM + k * 32 + kq * 8];
            e[0] = mfma16(Af, Bf[0][k], e[0]);
            e[1] = mfma16(Af, Bf[1][k], e[1]);
        }
        f32x4 rmx = *(const f32x4*)&rowmax[(size_t)b * NDIM + nb + kq * 4];
        f32x4 rsm = *(const f32x4*)&rowsum[(size_t)b * NDIM + nb + kq * 4];
#pragma unroll
        for (int mm = 0; mm < 2; ++mm) {
            f16x4 p;
#pragma unroll
            for (int r = 0; r < 4; ++r) {
                float a0 = __expf(e[mm][r] - rmx[r]) / rsm[r];
                csum[mm] += a0;
                p[r] = (f16)a0;
            }
            *(f16x4*)&attn_t[mm * 16 + row][wave * 16 + kq * 4] = p;
        }
        __syncthreads();
#pragma unroll
        for (int ks = 0; ks < 2; ++ks) {
            f16x8 Bp[2];
#pragma unroll
            for (int mm = 0; mm < 2; ++mm)
                Bp[mm] = *(const f16x8*)&attn_t[mm * 16 + row][ks * 32 + kq * 8];
#pragma unroll
            for (int cc = 0; cc < 4; ++cc) {
                const int c = wave * 64 + cc * 16;
                f16x8 Ap = *(const f16x8*)&vhb[(size_t)(c + row) * NDIM + n0 + ks * 32 + kq * 8];
                xacc[cc][0] = mfma16(Ap, Bp[0], xacc[cc][0]);
                xacc[cc][1] = mfma16(Ap, Bp[1], xacc[cc][1]);
            }
        }
    }
#pragma unroll
    for (int off = 16; off <= 32; off <<= 1)
#pragma unroll
        for (int mm = 0; mm < 2; ++mm) csum[mm] += __shfl_xor(csum[mm], off);
    if (lane < 16) {
#pragma unroll
        for (int mm = 0; mm < 2; ++mm) cred[wave][mm * 16 + lane] = csum[mm];
    }
    __syncthreads();
    if (threadIdx.x < 32) {
        float s = 0.f;
#pragma unroll
        for (int w = 0; w < 4; ++w) s += cred[w][threadIdx.x];
        cinv[threadIdx.x] = 1.f / (1e-9f + s);
    }
    __syncthreads();
#pragma unroll
    for (int mm = 0; mm < 2; ++mm) {
        float ci = cinv[mm * 16 + row];
        const int m = m0 + mm * 16 + row;
#pragma unroll
        for (int cc = 0; cc < 4; ++cc) {
            const int c = wave * 64 + cc * 16 + kq * 4;
            f16x4 p;
#pragma unroll
            for (int r = 0; r < 4; ++r) {
                float xv = x[((size_t)b * CDIM + c + r) * NDIM + m];
                p[r] = (f16)(xv - xacc[cc][mm][r] * ci);
            }
            *(f16x4*)&dh[((size_t)b * NDIM + m) * CDIM + c] = p;
        }
    }
}

// ---------------------------------------------------------------------------
// K4a (MFMA): t = Wt*d + bt ; bn ; feat = x + relu(bn)
// A = Wt[o][c], B = dh[n][c]. grid (N/64, C/64, B), 4 waves.
// ---------------------------------------------------------------------------
__global__ __launch_bounds__(256)
void k_tbn(const float* __restrict__ x, const f16* __restrict__ dh,
           const f16* __restrict__ wth, const float* __restrict__ bt,
           const float* __restrict__ gamma, const float* __restrict__ beta,
           float* __restrict__ feat)
{
    const int nt = blockIdx.x, ct = blockIdx.y, b = blockIdx.z;
    const int wave = threadIdx.x >> 6, lane = threadIdx.x & 63;
    const int row = lane & 15, kq = lane >> 4;
    const int n0 = nt * 64, o0 = ct * 64 + wave * 16;
    const f16* db = dh + (size_t)b * NDIM * CDIM;
    f32x4 acc[4];
#pragma unroll
    for (int j = 0; j < 4; ++j) acc[j] = (f32x4){0.f, 0.f, 0.f, 0.f};
#pragma unroll
    for (int k = 0; k < 8; ++k) {
        f16x8 A = *(const f16x8*)&wth[(size_t)(o0 + row) * CDIM + k * 32 + kq * 8];
#pragma unroll
        for (int j = 0; j < 4; ++j) {
            f16x8 B = *(const f16x8*)&db[(size_t)(n0 + j * 16 + row) * CDIM + k * 32 + kq * 8];
            acc[j] = mfma16(A, B, acc[j]);
        }
    }
    const float bnsc = 0.99999500003749968f; // 1/sqrt(1 + 1e-5)
#pragma unroll
    for (int j = 0; j < 4; ++j) {
        const int n = n0 + j * 16 + row;
#pragma unroll
        for (int r = 0; r < 4; ++r) {
            const int o = o0 + kq * 4 + r;
            float t = acc[j][r] + bt[o];
            float bn = t * bnsc * gamma[o] + beta[o];
            size_t off = ((size_t)b * CDIM + o) * NDIM + n;
            feat[off] = x[off] + fmaxf(bn, 0.f);
        }
    }
}

// ---------------------------------------------------------------------------
// K4b: query = Wproj*feat + bproj
// ---------------------------------------------------------------------------
__global__ __launch_bounds__(256)
void k_query(const float* __restrict__ feat, const float* __restrict__ Wp,
             const float* __restrict__ bp, float* __restrict__ query)
{
    __shared__ float wp_s[3 * CDIM];
    const int tid = threadIdx.x, b = blockIdx.y;
    for (int i = tid; i < 3 * CDIM; i += 256) wp_s[i] = Wp[i];
    __syncthreads();
    const int n = blockIdx.x * 256 + tid;
    float a0 = 0.f, a1 = 0.f, a2 = 0.f;
    const float* fb = feat + (size_t)b * CDIM * NDIM + n;
    for (int c = 0; c < CDIM; ++c) {
        float f = fb[(size_t)c * NDIM];
        a0 += wp_s[c] * f;
        a1 += wp_s[CDIM + c] * f;
        a2 += wp_s[2 * CDIM + c] * f;
    }
    query[((size_t)b * 3 + 0) * NDIM + n] = a0 + bp[0];
    query[((size_t)b * 3 + 1) * NDIM + n] = a1 + bp[1];
    query[((size_t)b * 3 + 2) * NDIM + n] = a2 + bp[2];
}

// ---------------------------------------------------------------------------
// K5 v3: one wave per query, no LDS. Lane scans 64 points (coalesced float4
// from global pt4), keeps sorted top-10; 10-round 64-lane tournament merge.
// grid (N/4, B), 256 thr = 4 waves = 4 queries.
// ---------------------------------------------------------------------------
__global__ __launch_bounds__(256)
void k_softproj(const float4* __restrict__ pt4, const float* __restrict__ query,
                const float* __restrict__ temp_p, float* __restrict__ out)
{
    const int wave = threadIdx.x >> 6, lane = threadIdx.x & 63;
    const int b = blockIdx.y;
    const int n = blockIdx.x * 4 + wave;
    const float4* ptb = pt4 + (size_t)b * MDIM;
    const float qx = query[((size_t)b * 3 + 0) * NDIM + n];
    const float qy = query[((size_t)b * 3 + 1) * NDIM + n];
    const float qz = query[((size_t)b * 3 + 2) * NDIM + n];
    const float q2 = qx * qx + qy * qy + qz * qz;

    float bd[KNN];
    int bi[KNN];
#pragma unroll
    for (int k = 0; k < KNN; ++k) { bd[k] = 3.4e38f; bi[k] = 0x7fffffff; }
#pragma unroll 4
    for (int i = 0; i < MDIM / 64; ++i) {
        const int m = i * 64 + lane;
        float4 p = ptb[m];
        float d2 = q2 + p.w - 2.0f * (qx * p.x + qy * p.y + qz * p.z);
        if (d2 < bd[KNN - 1]) {
            bd[KNN - 1] = d2; bi[KNN - 1] = m;
#pragma unroll
            for (int k = KNN - 1; k > 0; --k) {
                bool sw = bd[k] < bd[k - 1];
                float td = sw ? bd[k - 1] : bd[k];
                bd[k - 1] = sw ? bd[k] : bd[k - 1];
                bd[k] = td;
                int ti = sw ? bi[k - 1] : bi[k];
                bi[k - 1] = sw ? bi[k] : bi[k - 1];
                bi[k] = ti;
            }
        }
    }
    // 64-lane tournament merge: 10 winners
    int wi[KNN];
#pragma unroll
    for (int k = 0; k < KNN; ++k) {
        float d = bd[0];
        int idx = bi[0];
#pragma unroll
        for (int off = 1; off <= 32; off <<= 1) {
            float od = __shfl_xor(d, off);
            int oi = __shfl_xor(idx, off);
            if (od < d || (od == d && oi < idx)) { d = od; idx = oi; }
        }
        wi[k] = idx;
        bool won = (bd[0] == d) && (bi[0] == idx);
#pragma unroll
        for (int s = 0; s < KNN - 1; ++s) {
            bd[s] = won ? bd[s + 1] : bd[s];
            bi[s] = won ? bi[s + 1] : bi[s];
        }
        if (won) { bd[KNN - 1] = 3.4e38f; bi[KNN - 1] = 0x7fffffff; }
    }
    const float temp = temp_p[0];
    const float sigma = fmaxf(temp * temp, 1e-4f) + 1e-8f;
    const float inv_sig = 1.0f / sigma;
    float gx[KNN], gy[KNN], gz[KNN], dist[KNN];
#pragma unroll
    for (int k = 0; k < KNN; ++k) {
        float4 p = ptb[wi[k]];
        gx[k] = p.x; gy[k] = p.y; gz[k] = p.z;
        float dx = p.x - qx, dy = p.y - qy, dz = p.z - qz;
        dist[k] = (dx * dx + dy * dy + dz * dz) * inv_sig;
    }
    float mn = dist[0];
#pragma unroll
    for (int k = 1; k < KNN; ++k) mn = fminf(mn, dist[k]);
    float wsum = 0.f, ox = 0.f, oy = 0.f, oz = 0.f;
#pragma unroll
    for (int k = 0; k < KNN; ++k) {
        float w = __expf(mn - dist[k]);
        wsum += w; ox += w * gx[k]; oy += w * gy[k]; oz += w * gz[k];
    }
    if (lane == 0) {
        float invw = 1.0f / wsum;
        out[((size_t)b * 3 + 0) * NDIM + n] = ox * invw;
        out[((size_t)b * 3 + 1) * NDIM + n] = oy * invw;
        out[((size_t)b * 3 + 2) * NDIM + n] = oz * invw;
    }
}

// ---------------------------------------------------------------------------
extern "C" void kernel_launch(void* const* d_in, const int* in_sizes, int n_in,
                              void* d_out, int out_size, void* d_ws, size_t ws_size,
                              hipStream_t stream)
{
    const float* x     = (const float*)d_in[0];
    const float* pc    = (const float*)d_in[1];
    const float* Wqk   = (const float*)d_in[2];
    const float* Wv    = (const float*)d_in[3];
    const float* bv    = (const float*)d_in[4];
    const float* Wt    = (const float*)d_in[5];
    const float* bt    = (const float*)d_in[6];
    const float* gamma = (const float*)d_in[7];
    const float* beta  = (const float*)d_in[8];
    const float* Wp    = (const float*)d_in[9];
    const float* bp    = (const float*)d_in[10];
    const float* temp  = (const float*)d_in[11];
    float* out = (float*)d_out;

    char* w = (char*)d_ws;
    const size_t MB = 1024 * 1024;
    f16*    yt     = (f16*)(w);               // 8 MB [b][n][c]
    f16*    vh     = (f16*)(w + 8 * MB);      // 8 MB [b][c][n]
    f16*    dh     = (f16*)(w + 16 * MB);     // 8 MB [b][n][c]
    f16*    xt     = (f16*)(w + 24 * MB);     // 8 MB [b][n][c]
    f16*    wqh    = (f16*)(w + 32 * MB);     // 128 KB
    f16*    wvh    = wqh + 65536;
    f16*    wth    = wvh + 65536;
    float4* pt4    = (float4*)(w + 33 * MB);  // 512 KB
    float*  rowmax = (float*)(w + 34 * MB);
    float*  rowsum = rowmax + (size_t)BDIM * NDIM;
    float*  query  = rowsum + (size_t)BDIM * NDIM;
    float*  feat   = (float*)(w);             // 16 MB, aliases yt+vh (dead)

    k_prep_w<<<dim3(256), 256, 0, stream>>>(Wqk, Wv, Wt, wqh, wvh, wth);
    k_prep_pt<<<dim3(128), 256, 0, stream>>>(pc, pt4);
    k_xt<<<dim3(NDIM / 64, CDIM / 64, BDIM), 256, 0, stream>>>(x, xt);
    k_qkv<<<dim3(NDIM / 64, CDIM / 64, BDIM), 256, 0, stream>>>(xt, wqh, wvh, bv, yt, vh);
    k_rowstats<<<dim3(NDIM / 32, BDIM), 256, 0, stream>>>(yt, rowmax, rowsum);
    k_attn_xr<<<dim3(NDIM / 32, BDIM), 256, 0, stream>>>(yt, vh, rowmax, rowsum, x, dh);
    k_tbn<<<dim3(NDIM / 64, CDIM / 64, BDIM), 256, 0, stream>>>(x, dh, wth, bt, gamma, beta, feat);
    k_query<<<dim3(NDIM / 256, BDIM), 256, 0, stream>>>(feat, Wp, bp, query);
    k_softproj<<<dim3(NDIM / 4, BDIM), 256, 0, stream>>>(pt4, query, temp, out);
}

// Round 5
// 474.184 us; speedup vs baseline: 4.4182x; 1.0028x over previous
//
#include <hip/hip_runtime.h>
#include <math.h>

#define BDIM 8
#define CDIM 256
#define NDIM 2048
#define MDIM 4096
#define KNN 10

typedef _Float16 f16;
typedef f16  f16x8 __attribute__((ext_vector_type(8)));
typedef f16  f16x4 __attribute__((ext_vector_type(4)));
typedef float f32x4 __attribute__((ext_vector_type(4)));

__device__ __forceinline__ f32x4 mfma16(f16x8 a, f16x8 b, f32x4 c) {
    return __builtin_amdgcn_mfma_f32_16x16x32_f16(a, b, c, 0, 0, 0);
}

// ---------------------------------------------------------------------------
// P1: weights -> fp16
// ---------------------------------------------------------------------------
__global__ __launch_bounds__(256)
void k_prep_w(const float* __restrict__ Wqk, const float* __restrict__ Wv,
              const float* __restrict__ Wt,
              f16* __restrict__ wqh, f16* __restrict__ wvh, f16* __restrict__ wth)
{
    int i = blockIdx.x * 256 + threadIdx.x;
    wqh[i] = (f16)Wqk[i];
    wvh[i] = (f16)Wv[i];
    wth[i] = (f16)Wt[i];
}

// ---------------------------------------------------------------------------
// P2: pt4[b][m] = (x, y, z, |p|^2)
// ---------------------------------------------------------------------------
__global__ __launch_bounds__(256)
void k_prep_pt(const float* __restrict__ pc, float4* __restrict__ pt4)
{
    int i = blockIdx.x * 256 + threadIdx.x;
    int b = i >> 12, m = i & (MDIM - 1);
    const float* pb = pc + (size_t)b * 3 * MDIM;
    float a = pb[m], c = pb[MDIM + m], d = pb[2 * MDIM + m];
    pt4[i] = make_float4(a, c, d, a * a + c * c + d * d);
}

// ---------------------------------------------------------------------------
// P3: xt[b][n][c] = fp16(x[b][c][n])  via LDS tile transpose
// ---------------------------------------------------------------------------
__global__ __launch_bounds__(256)
void k_xt(const float* __restrict__ x, f16* __restrict__ xt)
{
    __shared__ float ls[64][68];
    const int nt = blockIdx.x, ct = blockIdx.y, b = blockIdx.z;
    const int tid = threadIdx.x;
    const int n0 = nt * 64, c0 = ct * 64;
    const int cl = tid >> 4, n4 = (tid & 15) * 4;
#pragma unroll
    for (int q = 0; q < 4; ++q) {
        int c = q * 16 + cl;
        *(float4*)&ls[c][n4] = *(const float4*)&x[((size_t)b * CDIM + c0 + c) * NDIM + n0 + n4];
    }
    __syncthreads();
    const int c4 = (tid & 15) * 4;
#pragma unroll
    for (int q = 0; q < 4; ++q) {
        int n = q * 16 + cl;
        f16x4 p;
#pragma unroll
        for (int r = 0; r < 4; ++r) p[r] = (f16)ls[c4 + r][n];
        *(f16x4*)&xt[((size_t)b * NDIM + n0 + n) * CDIM + c0 + c4] = p;
    }
}

// ---------------------------------------------------------------------------
// K1 (MFMA): y = Wqk*x ; v = Wv*x + bv. 1-D grid 1024: b = id&7 (XCD-local).
// ---------------------------------------------------------------------------
__global__ __launch_bounds__(256)
void k_qkv(const f16* __restrict__ xt, const f16* __restrict__ wqh,
           const f16* __restrict__ wvh, const float* __restrict__ bv,
           f16* __restrict__ yt, f16* __restrict__ vh)
{
    const int id = blockIdx.x;
    const int b = id & 7, nt = (id >> 3) & 31, ct = id >> 8;
    const int wave = threadIdx.x >> 6, lane = threadIdx.x & 63;
    const int row = lane & 15, kq = lane >> 4;
    const int n0 = nt * 64, o0 = ct * 64 + wave * 16;
    const f16* xb = xt + (size_t)b * NDIM * CDIM;
    f32x4 accy[4], accv[4];
#pragma unroll
    for (int j = 0; j < 4; ++j) {
        accy[j] = (f32x4){0.f, 0.f, 0.f, 0.f};
        accv[j] = (f32x4){0.f, 0.f, 0.f, 0.f};
    }
#pragma unroll
    for (int k = 0; k < 8; ++k) {
        f16x8 Aq = *(const f16x8*)&wqh[(size_t)(o0 + row) * CDIM + k * 32 + kq * 8];
        f16x8 Av = *(const f16x8*)&wvh[(size_t)(o0 + row) * CDIM + k * 32 + kq * 8];
#pragma unroll
        for (int j = 0; j < 4; ++j) {
            f16x8 Bx = *(const f16x8*)&xb[(size_t)(n0 + j * 16 + row) * CDIM + k * 32 + kq * 8];
            accy[j] = mfma16(Aq, Bx, accy[j]);
            accv[j] = mfma16(Av, Bx, accv[j]);
        }
    }
#pragma unroll
    for (int j = 0; j < 4; ++j) {
        const int n = n0 + j * 16 + row;
        f16x4 p;
#pragma unroll
        for (int r = 0; r < 4; ++r) p[r] = (f16)accy[j][r];
        *(f16x4*)&yt[((size_t)b * NDIM + n) * CDIM + o0 + kq * 4] = p;
#pragma unroll
        for (int r = 0; r < 4; ++r) {
            const int o = o0 + kq * 4 + r;
            vh[((size_t)b * CDIM + o) * NDIM + n] = (f16)(accv[j][r] + bv[o]);
        }
    }
}

// ---------------------------------------------------------------------------
// K1b: diag[b][n] = |y_n|^2 (softmax offset; exact max not needed, only
// overflow safety — diag dominates off-diag by construction).
// grid B*N/4, 4 waves, one wave per row.
// ---------------------------------------------------------------------------
__global__ __launch_bounds__(256)
void k_ynorm(const f16* __restrict__ yt, float* __restrict__ diag)
{
    const int wave = threadIdx.x >> 6, lane = threadIdx.x & 63;
    const int id = blockIdx.x * 4 + wave;              // [0, B*N)
    f16x4 p = *(const f16x4*)&yt[(size_t)id * CDIM + lane * 4];
    float s = 0.f;
#pragma unroll
    for (int r = 0; r < 4; ++r) { float v = (float)p[r]; s += v * v; }
#pragma unroll
    for (int off = 1; off <= 32; off <<= 1) s += __shfl_xor(s, off);
    if (lane == 0) diag[id] = s;
}

// ---------------------------------------------------------------------------
// K2 (MFMA): rowsum[m] = sum_n exp(E[m][n] - diag[m]) via symmetry.
// 1-D grid 512: b = id&7 -> all blocks of batch b on XCD b (yt L2-resident).
// ---------------------------------------------------------------------------
__global__ __launch_bounds__(256)
void k_rowstats(const f16* __restrict__ yt, const float* __restrict__ diag,
                float* __restrict__ rowsum)
{
    const int id = blockIdx.x;
    const int b = id & 7, mt = id >> 3;
    const int wave = threadIdx.x >> 6, lane = threadIdx.x & 63;
    const int m0 = mt * 32;
    const int row = lane & 15, kq = lane >> 4;
    const f16* ytb = yt + (size_t)b * NDIM * CDIM;
    f16x8 Bf[2][8];
#pragma unroll
    for (int mm = 0; mm < 2; ++mm)
#pragma unroll
        for (int k = 0; k < 8; ++k)
            Bf[mm][k] = *(const f16x8*)&ytb[(size_t)(m0 + mm * 16 + row) * CDIM + k * 32 + kq * 8];
    const float dmx[2] = { diag[(size_t)b * NDIM + m0 + row],
                           diag[(size_t)b * NDIM + m0 + 16 + row] };
    float sm[2] = {0.f, 0.f};
    for (int it = wave; it < NDIM / 16; it += 4) {
        const int n0 = it * 16;
        f32x4 acc[2] = {{0.f, 0.f, 0.f, 0.f}, {0.f, 0.f, 0.f, 0.f}};
#pragma unroll
        for (int k = 0; k < 8; ++k) {
            f16x8 Af = *(const f16x8*)&ytb[(size_t)(n0 + row) * CDIM + k * 32 + kq * 8];
            acc[0] = mfma16(Af, Bf[0][k], acc[0]);
            acc[1] = mfma16(Af, Bf[1][k], acc[1]);
        }
#pragma unroll
        for (int mm = 0; mm < 2; ++mm) {
#pragma unroll
            for (int r = 0; r < 4; ++r) sm[mm] += __expf(acc[mm][r] - dmx[mm]);
        }
    }
#pragma unroll
    for (int off = 16; off <= 32; off <<= 1)
#pragma unroll
        for (int mm = 0; mm < 2; ++mm) sm[mm] += __shfl_xor(sm[mm], off);
    __shared__ float ssm[4][32];
    if (lane < 16) {
#pragma unroll
        for (int mm = 0; mm < 2; ++mm) ssm[wave][mm * 16 + lane] = sm[mm];
    }
    __syncthreads();
    if (threadIdx.x < 32) {
        float S = 0.f;
#pragma unroll
        for (int w = 0; w < 4; ++w) S += ssm[w][threadIdx.x];
        rowsum[(size_t)b * NDIM + m0 + threadIdx.x] = S;
    }
}

// ---------------------------------------------------------------------------
// K3 (MFMA): energy -> attn(fp16, LDS) -> PV; epilogue emits dh = fp16(x-xr).
// 1-D grid 512: b = id&7 (yt+vh = 2 MB L2-resident per XCD).
// ---------------------------------------------------------------------------
__global__ __launch_bounds__(256)
void k_attn_xr(const f16* __restrict__ yt, const f16* __restrict__ vh,
               const float* __restrict__ diag, const float* __restrict__ rowsum,
               const f16* __restrict__ xt, f16* __restrict__ dh)
{
    const int id = blockIdx.x;
    const int b = id & 7, mt = id >> 3;
    const int wave = threadIdx.x >> 6, lane = threadIdx.x & 63;
    const int m0 = mt * 32;
    const int row = lane & 15, kq = lane >> 4;
    const f16* ytb = yt + (size_t)b * NDIM * CDIM;
    const f16* vhb = vh + (size_t)b * CDIM * NDIM;
    __shared__ __align__(16) f16 attn_t[32][72];
    __shared__ float cred[4][32];
    __shared__ float cinv[32];
    f16x8 Bf[2][8];
#pragma unroll
    for (int mm = 0; mm < 2; ++mm)
#pragma unroll
        for (int k = 0; k < 8; ++k)
            Bf[mm][k] = *(const f16x8*)&ytb[(size_t)(m0 + mm * 16 + row) * CDIM + k * 32 + kq * 8];
    f32x4 xacc[4][2];
#pragma unroll
    for (int cc = 0; cc < 4; ++cc)
#pragma unroll
        for (int mm = 0; mm < 2; ++mm) xacc[cc][mm] = (f32x4){0.f, 0.f, 0.f, 0.f};
    float csum[2] = {0.f, 0.f};

    for (int it = 0; it < NDIM / 64; ++it) {
        const int n0 = it * 64;
        const int nb = n0 + wave * 16;
        __syncthreads();
        f32x4 e[2] = {{0.f, 0.f, 0.f, 0.f}, {0.f, 0.f, 0.f, 0.f}};
#pragma unroll
        for (int k = 0; k < 8; ++k) {
            f16x8 Af = *(const f16x8*)&ytb[(size_t)(nb + row) * CDIM + k * 32 + kq * 8];
            e[0] = mfma16(Af, Bf[0][k], e[0]);
            e[1] = mfma16(Af, Bf[1][k], e[1]);
        }
        f32x4 rmx = *(const f32x4*)&diag[(size_t)b * NDIM + nb + kq * 4];
        f32x4 rsm = *(const f32x4*)&rowsum[(size_t)b * NDIM + nb + kq * 4];
#pragma unroll
        for (int mm = 0; mm < 2; ++mm) {
            f16x4 p;
#pragma unroll
            for (int r = 0; r < 4; ++r) {
                float a0 = __expf(e[mm][r] - rmx[r]) / rsm[r];
                csum[mm] += a0;
                p[r] = (f16)a0;
            }
            *(f16x4*)&attn_t[mm * 16 + row][wave * 16 + kq * 4] = p;
        }
        __syncthreads();
#pragma unroll
        for (int ks = 0; ks < 2; ++ks) {
            f16x8 Bp[2];
#pragma unroll
            for (int mm = 0; mm < 2; ++mm)
                Bp[mm] = *(const f16x8*)&attn_t[mm * 16 + row][ks * 32 + kq * 8];
#pragma unroll
            for (int cc = 0; cc < 4; ++cc) {
                const int c = wave * 64 + cc * 16;
                f16x8 Ap = *(const f16x8*)&vhb[(size_t)(c + row) * NDIM + n0 + ks * 32 + kq * 8];
                xacc[cc][0] = mfma16(Ap, Bp[0], xacc[cc][0]);
                xacc[cc][1] = mfma16(Ap, Bp[1], xacc[cc][1]);
            }
        }
    }
#pragma unroll
    for (int off = 16; off <= 32; off <<= 1)
#pragma unroll
        for (int mm = 0; mm < 2; ++mm) csum[mm] += __shfl_xor(csum[mm], off);
    if (lane < 16) {
#pragma unroll
        for (int mm = 0; mm < 2; ++mm) cred[wave][mm * 16 + lane] = csum[mm];
    }
    __syncthreads();
    if (threadIdx.x < 32) {
        float s = 0.f;
#pragma unroll
        for (int w = 0; w < 4; ++w) s += cred[w][threadIdx.x];
        cinv[threadIdx.x] = 1.f / (1e-9f + s);
    }
    __syncthreads();
#pragma unroll
    for (int mm = 0; mm < 2; ++mm) {
        float ci = cinv[mm * 16 + row];
        const int m = m0 + mm * 16 + row;
#pragma unroll
        for (int cc = 0; cc < 4; ++cc) {
            const int c = wave * 64 + cc * 16 + kq * 4;
            f16x4 xv = *(const f16x4*)&xt[((size_t)b * NDIM + m) * CDIM + c];
            f16x4 p;
#pragma unroll
            for (int r = 0; r < 4; ++r)
                p[r] = (f16)((float)xv[r] - xacc[cc][mm][r] * ci);
            *(f16x4*)&dh[((size_t)b * NDIM + m) * CDIM + c] = p;
        }
    }
}

// ---------------------------------------------------------------------------
// K4a (MFMA): t = Wt*d + bt ; bn ; feat = x + relu(bn). 1-D grid, b = id&7.
// ---------------------------------------------------------------------------
__global__ __launch_bounds__(256)
void k_tbn(const float* __restrict__ x, const f16* __restrict__ dh,
           const f16* __restrict__ wth, const float* __restrict__ bt,
           const float* __restrict__ gamma, const float* __restrict__ beta,
           float* __restrict__ feat)
{
    const int id = blockIdx.x;
    const int b = id & 7, nt = (id >> 3) & 31, ct = id >> 8;
    const int wave = threadIdx.x >> 6, lane = threadIdx.x & 63;
    const int row = lane & 15, kq = lane >> 4;
    const int n0 = nt * 64, o0 = ct * 64 + wave * 16;
    const f16* db = dh + (size_t)b * NDIM * CDIM;
    f32x4 acc[4];
#pragma unroll
    for (int j = 0; j < 4; ++j) acc[j] = (f32x4){0.f, 0.f, 0.f, 0.f};
#pragma unroll
    for (int k = 0; k < 8; ++k) {
        f16x8 A = *(const f16x8*)&wth[(size_t)(o0 + row) * CDIM + k * 32 + kq * 8];
#pragma unroll
        for (int j = 0; j < 4; ++j) {
            f16x8 B = *(const f16x8*)&db[(size_t)(n0 + j * 16 + row) * CDIM + k * 32 + kq * 8];
            acc[j] = mfma16(A, B, acc[j]);
        }
    }
    const float bnsc = 0.99999500003749968f; // 1/sqrt(1 + 1e-5)
#pragma unroll
    for (int j = 0; j < 4; ++j) {
        const int n = n0 + j * 16 + row;
#pragma unroll
        for (int r = 0; r < 4; ++r) {
            const int o = o0 + kq * 4 + r;
            float t = acc[j][r] + bt[o];
            float bn = t * bnsc * gamma[o] + beta[o];
            size_t off = ((size_t)b * CDIM + o) * NDIM + n;
            feat[off] = x[off] + fmaxf(bn, 0.f);
        }
    }
}

// ---------------------------------------------------------------------------
// K4b: query = Wproj*feat + bproj
// ---------------------------------------------------------------------------
__global__ __launch_bounds__(256)
void k_query(const float* __restrict__ feat, const float* __restrict__ Wp,
             const float* __restrict__ bp, float* __restrict__ query)
{
    __shared__ float wp_s[3 * CDIM];
    const int tid = threadIdx.x, b = blockIdx.y;
    for (int i = tid; i < 3 * CDIM; i += 256) wp_s[i] = Wp[i];
    __syncthreads();
    const int n = blockIdx.x * 256 + tid;
    float a0 = 0.f, a1 = 0.f, a2 = 0.f;
    const float* fb = feat + (size_t)b * CDIM * NDIM + n;
    for (int c = 0; c < CDIM; ++c) {
        float f = fb[(size_t)c * NDIM];
        a0 += wp_s[c] * f;
        a1 += wp_s[CDIM + c] * f;
        a2 += wp_s[2 * CDIM + c] * f;
    }
    query[((size_t)b * 3 + 0) * NDIM + n] = a0 + bp[0];
    query[((size_t)b * 3 + 1) * NDIM + n] = a1 + bp[1];
    query[((size_t)b * 3 + 2) * NDIM + n] = a2 + bp[2];
}

// ---------------------------------------------------------------------------
// K5: one wave per query; lane scans 64 pts; 64-lane tournament merge.
// ---------------------------------------------------------------------------
__global__ __launch_bounds__(256)
void k_softproj(const float4* __restrict__ pt4, const float* __restrict__ query,
                const float* __restrict__ temp_p, float* __restrict__ out)
{
    const int wave = threadIdx.x >> 6, lane = threadIdx.x & 63;
    const int b = blockIdx.y;
    const int n = blockIdx.x * 4 + wave;
    const float4* ptb = pt4 + (size_t)b * MDIM;
    const float qx = query[((size_t)b * 3 + 0) * NDIM + n];
    const float qy = query[((size_t)b * 3 + 1) * NDIM + n];
    const float qz = query[((size_t)b * 3 + 2) * NDIM + n];
    const float q2 = qx * qx + qy * qy + qz * qz;

    float bd[KNN];
    int bi[KNN];
#pragma unroll
    for (int k = 0; k < KNN; ++k) { bd[k] = 3.4e38f; bi[k] = 0x7fffffff; }
#pragma unroll 4
    for (int i = 0; i < MDIM / 64; ++i) {
        const int m = i * 64 + lane;
        float4 p = ptb[m];
        float d2 = q2 + p.w - 2.0f * (qx * p.x + qy * p.y + qz * p.z);
        if (d2 < bd[KNN - 1]) {
            bd[KNN - 1] = d2; bi[KNN - 1] = m;
#pragma unroll
            for (int k = KNN - 1; k > 0; --k) {
                bool sw = bd[k] < bd[k - 1];
                float td = sw ? bd[k - 1] : bd[k];
                bd[k - 1] = sw ? bd[k] : bd[k - 1];
                bd[k] = td;
                int ti = sw ? bi[k - 1] : bi[k];
                bi[k - 1] = sw ? bi[k] : bi[k - 1];
                bi[k] = ti;
            }
        }
    }
    int wi[KNN];
#pragma unroll
    for (int k = 0; k < KNN; ++k) {
        float d = bd[0];
        int idx = bi[0];
#pragma unroll
        for (int off = 1; off <= 32; off <<= 1) {
            float od = __shfl_xor(d, off);
            int oi = __shfl_xor(idx, off);
            if (od < d || (od == d && oi < idx)) { d = od; idx = oi; }
        }
        wi[k] = idx;
        bool won = (bd[0] == d) && (bi[0] == idx);
#pragma unroll
        for (int s = 0; s < KNN - 1; ++s) {
            bd[s] = won ? bd[s + 1] : bd[s];
            bi[s] = won ? bi[s + 1] : bi[s];
        }
        if (won) { bd[KNN - 1] = 3.4e38f; bi[KNN - 1] = 0x7fffffff; }
    }
    const float temp = temp_p[0];
    const float sigma = fmaxf(temp * temp, 1e-4f) + 1e-8f;
    const float inv_sig = 1.0f / sigma;
    float gx[KNN], gy[KNN], gz[KNN], dist[KNN];
#pragma unroll
    for (int k = 0; k < KNN; ++k) {
        float4 p = ptb[wi[k]];
        gx[k] = p.x; gy[k] = p.y; gz[k] = p.z;
        float dx = p.x - qx, dy = p.y - qy, dz = p.z - qz;
        dist[k] = (dx * dx + dy * dy + dz * dz) * inv_sig;
    }
    float mn = dist[0];
#pragma unroll
    for (int k = 1; k < KNN; ++k) mn = fminf(mn, dist[k]);
    float wsum = 0.f, ox = 0.f, oy = 0.f, oz = 0.f;
#pragma unroll
    for (int k = 0; k < KNN; ++k) {
        float w = __expf(mn - dist[k]);
        wsum += w; ox += w * gx[k]; oy += w * gy[k]; oz += w * gz[k];
    }
    if (lane == 0) {
        float invw = 1.0f / wsum;
        out[((size_t)b * 3 + 0) * NDIM + n] = ox * invw;
        out[((size_t)b * 3 + 1) * NDIM + n] = oy * invw;
        out[((size_t)b * 3 + 2) * NDIM + n] = oz * invw;
    }
}

// ---------------------------------------------------------------------------
extern "C" void kernel_launch(void* const* d_in, const int* in_sizes, int n_in,
                              void* d_out, int out_size, void* d_ws, size_t ws_size,
                              hipStream_t stream)
{
    const float* x     = (const float*)d_in[0];
    const float* pc    = (const float*)d_in[1];
    const float* Wqk   = (const float*)d_in[2];
    const float* Wv    = (const float*)d_in[3];
    const float* bv    = (const float*)d_in[4];
    const float* Wt    = (const float*)d_in[5];
    const float* bt    = (const float*)d_in[6];
    const float* gamma = (const float*)d_in[7];
    const float* beta  = (const float*)d_in[8];
    const float* Wp    = (const float*)d_in[9];
    const float* bp    = (const float*)d_in[10];
    const float* temp  = (const float*)d_in[11];
    float* out = (float*)d_out;

    char* w = (char*)d_ws;
    const size_t MB = 1024 * 1024;
    f16*    yt     = (f16*)(w);               // 8 MB [b][n][c]
    f16*    vh     = (f16*)(w + 8 * MB);      // 8 MB [b][c][n]
    f16*    dh     = (f16*)(w + 16 * MB);     // 8 MB [b][n][c]
    f16*    xt     = (f16*)(w + 24 * MB);     // 8 MB [b][n][c]
    f16*    wqh    = (f16*)(w + 32 * MB);     // 128 KB
    f16*    wvh    = wqh + 65536;
    f16*    wth    = wvh + 65536;
    float4* pt4    = (float4*)(w + 33 * MB);  // 512 KB
    float*  diag   = (float*)(w + 34 * MB);   // 64 KB
    float*  rowsum = diag + (size_t)BDIM * NDIM;
    float*  query  = rowsum + (size_t)BDIM * NDIM;
    float*  feat   = (float*)(w);             // 16 MB, aliases yt+vh (dead)

    k_prep_w<<<dim3(256), 256, 0, stream>>>(Wqk, Wv, Wt, wqh, wvh, wth);
    k_prep_pt<<<dim3(128), 256, 0, stream>>>(pc, pt4);
    k_xt<<<dim3(NDIM / 64, CDIM / 64, BDIM), 256, 0, stream>>>(x, xt);
    k_qkv<<<dim3(1024), 256, 0, stream>>>(xt, wqh, wvh, bv, yt, vh);
    k_ynorm<<<dim3(BDIM * NDIM / 4), 256, 0, stream>>>(yt, diag);
    k_rowstats<<<dim3(512), 256, 0, stream>>>(yt, diag, rowsum);
    k_attn_xr<<<dim3(512), 256, 0, stream>>>(yt, vh, diag, rowsum, xt, dh);
    k_tbn<<<dim3(1024), 256, 0, stream>>>(x, dh, wth, bt, gamma, beta, feat);
    k_query<<<dim3(NDIM / 256, BDIM), 256, 0, stream>>>(feat, Wp, bp, query);
    k_softproj<<<dim3(NDIM / 4, BDIM), 256, 0, stream>>>(pt4, query, temp, out);
}

// Round 6
// 393.094 us; speedup vs baseline: 5.3296x; 1.2063x over previous
//
#include <hip/hip_runtime.h>
#include <math.h>

#define BDIM 8
#define CDIM 256
#define NDIM 2048
#define MDIM 4096
#define KNN 10

typedef _Float16 f16;
typedef f16  f16x8 __attribute__((ext_vector_type(8)));
typedef f16  f16x4 __attribute__((ext_vector_type(4)));
typedef float f32x4 __attribute__((ext_vector_type(4)));

__device__ __forceinline__ f32x4 mfma16(f16x8 a, f16x8 b, f32x4 c) {
    return __builtin_amdgcn_mfma_f32_16x16x32_f16(a, b, c, 0, 0, 0);
}

// Tiled fp16 layout: T[R/16][K/32][16][32]; element (r,k) at
// ((r>>4)*(K/32) + (k>>5))*512 + (r&15)*32 + (k&31).
// MFMA A/B fragment for (r0=16-aligned, 32-k-block kt) = contiguous 1KB:
// lane(row,kq) reads 16B at tile*512 + row*32 + kq*8.   [coalesced]

// ---------------------------------------------------------------------------
// P1: weights -> fp16 tiled [o/16][c/32][16][32]
// ---------------------------------------------------------------------------
__global__ __launch_bounds__(256)
void k_prep_w(const float* __restrict__ Wqk, const float* __restrict__ Wv,
              const float* __restrict__ Wt,
              f16* __restrict__ wqh, f16* __restrict__ wvh, f16* __restrict__ wth)
{
    int i = blockIdx.x * 256 + threadIdx.x;
    int o = i >> 8, c = i & 255;
    int idx = (((o >> 4) * 8 + (c >> 5)) << 9) + (o & 15) * 32 + (c & 31);
    wqh[idx] = (f16)Wqk[i];
    wvh[idx] = (f16)Wv[i];
    wth[idx] = (f16)Wt[i];
}

// ---------------------------------------------------------------------------
// P2: pt4[b][m] = (x, y, z, |p|^2)
// ---------------------------------------------------------------------------
__global__ __launch_bounds__(256)
void k_prep_pt(const float* __restrict__ pc, float4* __restrict__ pt4)
{
    int i = blockIdx.x * 256 + threadIdx.x;
    int b = i >> 12, m = i & (MDIM - 1);
    const float* pb = pc + (size_t)b * 3 * MDIM;
    float a = pb[m], c = pb[MDIM + m], d = pb[2 * MDIM + m];
    pt4[i] = make_float4(a, c, d, a * a + c * c + d * d);
}

// ---------------------------------------------------------------------------
// P3: xt = fp16(x^T) in tiled layout [n/16][c/32][16][32] per batch
// ---------------------------------------------------------------------------
__global__ __launch_bounds__(256)
void k_xt(const float* __restrict__ x, f16* __restrict__ xt)
{
    __shared__ float ls[64][68];
    const int nt = blockIdx.x, ct = blockIdx.y, b = blockIdx.z;
    const int tid = threadIdx.x;
    const int n0 = nt * 64, c0 = ct * 64;
    const int cl = tid >> 4, n4 = (tid & 15) * 4;
#pragma unroll
    for (int q = 0; q < 4; ++q) {
        int c = q * 16 + cl;
        *(float4*)&ls[c][n4] = *(const float4*)&x[((size_t)b * CDIM + c0 + c) * NDIM + n0 + n4];
    }
    __syncthreads();
    f16* xb = xt + (size_t)b * NDIM * CDIM;
    const int c4 = (tid & 15) * 4;
    const int cg = c0 + c4;
#pragma unroll
    for (int q = 0; q < 4; ++q) {
        f16x4 p;
#pragma unroll
        for (int r = 0; r < 4; ++r) p[r] = (f16)ls[c4 + r][q * 16 + cl];
        xb[(((nt * 4 + q) * 8 + (cg >> 5)) << 9) + cl * 32 + (cg & 31) + 0] = p[0];
        *(f16x4*)&xb[(((nt * 4 + q) * 8 + (cg >> 5)) << 9) + cl * 32 + (cg & 31)] = p;
    }
}

// ---------------------------------------------------------------------------
// K1 (MFMA): y = Wqk*x ; v = Wv*x + bv.  All operands tiled -> coalesced.
// grid 1024 1-D: b = id&7 (XCD-local). yt tiled [n/16][c/32]; vh tiled
// [c/16][n/32].
// ---------------------------------------------------------------------------
__global__ __launch_bounds__(256)
void k_qkv(const f16* __restrict__ xt, const f16* __restrict__ wqh,
           const f16* __restrict__ wvh, const float* __restrict__ bv,
           f16* __restrict__ yt, f16* __restrict__ vh)
{
    const int id = blockIdx.x;
    const int b = id & 7, nt = (id >> 3) & 31, ct = id >> 8;
    const int wave = threadIdx.x >> 6, lane = threadIdx.x & 63;
    const int row = lane & 15, kq = lane >> 4;
    const int lo = row * 32 + kq * 8;
    const int n0 = nt * 64;
    const int ot = ct * 4 + wave;                 // o-tile (o0 = ot*16)
    const f16* xb = xt + (size_t)b * NDIM * CDIM;
    f16* ytb = yt + (size_t)b * NDIM * CDIM;
    f16* vhb = vh + (size_t)b * CDIM * NDIM;
    f32x4 accy[4], accv[4];
#pragma unroll
    for (int j = 0; j < 4; ++j) {
        accy[j] = (f32x4){0.f, 0.f, 0.f, 0.f};
        accv[j] = (f32x4){0.f, 0.f, 0.f, 0.f};
    }
#pragma unroll
    for (int k = 0; k < 8; ++k) {
        f16x8 Aq = *(const f16x8*)&wqh[((ot * 8 + k) << 9) + lo];
        f16x8 Av = *(const f16x8*)&wvh[((ot * 8 + k) << 9) + lo];
#pragma unroll
        for (int j = 0; j < 4; ++j) {
            f16x8 Bx = *(const f16x8*)&xb[((((nt * 4) + j) * 8 + k) << 9) + lo];
            accy[j] = mfma16(Aq, Bx, accy[j]);
            accv[j] = mfma16(Av, Bx, accv[j]);
        }
    }
    const int o0 = ot * 16;
    const int yin = (o0 & 31) + kq * 4;           // inner c offset in yt tile
#pragma unroll
    for (int j = 0; j < 4; ++j) {
        f16x4 p;
#pragma unroll
        for (int r = 0; r < 4; ++r) p[r] = (f16)accy[j][r];
        *(f16x4*)&ytb[((((nt * 4) + j) * 8 + (o0 >> 5)) << 9) + row * 32 + yin] = p;
#pragma unroll
        for (int r = 0; r < 4; ++r) {
            const int o = o0 + kq * 4 + r;
            const int n = n0 + j * 16 + row;
            vhb[((ot * 64 + (n >> 5)) << 9) + (kq * 4 + r) * 32 + (n & 31)] =
                (f16)(accv[j][r] + bv[o]);
        }
    }
}

// ---------------------------------------------------------------------------
// K1b: diag[b][n] = |y_n|^2 (softmax shift; diag dominates off-diag)
// ---------------------------------------------------------------------------
__global__ __launch_bounds__(256)
void k_ynorm(const f16* __restrict__ yt, float* __restrict__ diag)
{
    const int wave = threadIdx.x >> 6, lane = threadIdx.x & 63;
    const int id = blockIdx.x * 4 + wave;              // [0, B*N)
    const int n = id & (NDIM - 1);
    const f16* base = yt + (size_t)(id >> 11) * NDIM * CDIM;
    f16x4 p = *(const f16x4*)&base[(((n >> 4) * 8 + (lane >> 3)) << 9)
                                   + (n & 15) * 32 + (lane & 7) * 4];
    float s = 0.f;
#pragma unroll
    for (int r = 0; r < 4; ++r) { float v = (float)p[r]; s += v * v; }
#pragma unroll
    for (int off = 1; off <= 32; off <<= 1) s += __shfl_xor(s, off);
    if (lane == 0) diag[id] = s;
}

// ---------------------------------------------------------------------------
// K2 (MFMA): rowsum[m] = sum_n exp(E[m][n] - diag[m]).  Tiled loads,
// 2 n-tiles per step for ILP. grid 512: b = id&7.
// ---------------------------------------------------------------------------
__global__ __launch_bounds__(256)
void k_rowstats(const f16* __restrict__ yt, const float* __restrict__ diag,
                float* __restrict__ rowsum)
{
    const int id = blockIdx.x;
    const int b = id & 7, mt = id >> 3;                // m0 = mt*32
    const int wave = threadIdx.x >> 6, lane = threadIdx.x & 63;
    const int row = lane & 15, kq = lane >> 4;
    const int lo = row * 32 + kq * 8;
    const f16* ytb = yt + (size_t)b * NDIM * CDIM;
    f16x8 Bf[2][8];
#pragma unroll
    for (int mm = 0; mm < 2; ++mm)
#pragma unroll
        for (int k = 0; k < 8; ++k)
            Bf[mm][k] = *(const f16x8*)&ytb[(((mt * 2 + mm) * 8 + k) << 9) + lo];
    const float dmx[2] = { diag[(size_t)b * NDIM + mt * 32 + row],
                           diag[(size_t)b * NDIM + mt * 32 + 16 + row] };
    float sm[2] = {0.f, 0.f};
    for (int it = wave; it < NDIM / 16; it += 8) {
        const int it2 = it + 4;
        f32x4 acc[2][2];
#pragma unroll
        for (int u = 0; u < 2; ++u)
#pragma unroll
            for (int mm = 0; mm < 2; ++mm) acc[u][mm] = (f32x4){0.f, 0.f, 0.f, 0.f};
#pragma unroll
        for (int k = 0; k < 8; ++k) {
            f16x8 A1 = *(const f16x8*)&ytb[((it  * 8 + k) << 9) + lo];
            f16x8 A2 = *(const f16x8*)&ytb[((it2 * 8 + k) << 9) + lo];
            acc[0][0] = mfma16(A1, Bf[0][k], acc[0][0]);
            acc[0][1] = mfma16(A1, Bf[1][k], acc[0][1]);
            acc[1][0] = mfma16(A2, Bf[0][k], acc[1][0]);
            acc[1][1] = mfma16(A2, Bf[1][k], acc[1][1]);
        }
#pragma unroll
        for (int u = 0; u < 2; ++u)
#pragma unroll
            for (int mm = 0; mm < 2; ++mm)
#pragma unroll
                for (int r = 0; r < 4; ++r) sm[mm] += __expf(acc[u][mm][r] - dmx[mm]);
    }
#pragma unroll
    for (int off = 16; off <= 32; off <<= 1)
#pragma unroll
        for (int mm = 0; mm < 2; ++mm) sm[mm] += __shfl_xor(sm[mm], off);
    __shared__ float ssm[4][32];
    if (lane < 16) {
#pragma unroll
        for (int mm = 0; mm < 2; ++mm) ssm[wave][mm * 16 + lane] = sm[mm];
    }
    __syncthreads();
    if (threadIdx.x < 32) {
        float S = 0.f;
#pragma unroll
        for (int w = 0; w < 4; ++w) S += ssm[w][threadIdx.x];
        rowsum[(size_t)b * NDIM + mt * 32 + threadIdx.x] = S;
    }
}

// ---------------------------------------------------------------------------
// K3 (MFMA): energy -> attn -> PV, double-buffered attn LDS, ONE barrier per
// 64-n chunk, prefetched energy loads. Epilogue: dh = fp16(x - xr), tiled.
// grid 512: b = id&7.
// ---------------------------------------------------------------------------
__global__ __launch_bounds__(256)
void k_attn_xr(const f16* __restrict__ yt, const f16* __restrict__ vh,
               const float* __restrict__ diag, const float* __restrict__ rowsum,
               const f16* __restrict__ xt, f16* __restrict__ dh)
{
    const int id = blockIdx.x;
    const int b = id & 7, mt = id >> 3;                // m0 = mt*32
    const int wave = threadIdx.x >> 6, lane = threadIdx.x & 63;
    const int row = lane & 15, kq = lane >> 4;
    const int lo = row * 32 + kq * 8;
    const f16* ytb = yt + (size_t)b * NDIM * CDIM;
    const f16* vhb = vh + (size_t)b * CDIM * NDIM;
    const float* dgb = diag + (size_t)b * NDIM;
    const float* rsb = rowsum + (size_t)b * NDIM;
    __shared__ __align__(16) f16 attn_s[2][32][72];
    __shared__ float cred[4][32];
    __shared__ float cinv[32];
    f16x8 Bf[2][8];
#pragma unroll
    for (int mm = 0; mm < 2; ++mm)
#pragma unroll
        for (int k = 0; k < 8; ++k)
            Bf[mm][k] = *(const f16x8*)&ytb[(((mt * 2 + mm) * 8 + k) << 9) + lo];
    f32x4 xacc[4][2];
#pragma unroll
    for (int cc = 0; cc < 4; ++cc)
#pragma unroll
        for (int mm = 0; mm < 2; ++mm) xacc[cc][mm] = (f32x4){0.f, 0.f, 0.f, 0.f};
    float csum[2] = {0.f, 0.f};

    // energy(0)
    f32x4 e0 = {0.f, 0.f, 0.f, 0.f}, e1 = {0.f, 0.f, 0.f, 0.f};
#pragma unroll
    for (int k = 0; k < 8; ++k) {
        f16x8 Af = *(const f16x8*)&ytb[((wave * 8 + k) << 9) + lo];
        e0 = mfma16(Af, Bf[0][k], e0);
        e1 = mfma16(Af, Bf[1][k], e1);
    }

    for (int it = 0; it < NDIM / 64; ++it) {
        const int buf = it & 1;
        const int nb = it * 64 + wave * 16;
        // attn(it) from e, write attn_s[buf]
        f32x4 rmx = *(const f32x4*)&dgb[nb + kq * 4];
        f32x4 rsm = *(const f32x4*)&rsb[nb + kq * 4];
        {
            f16x4 p;
#pragma unroll
            for (int r = 0; r < 4; ++r) {
                float a0 = __expf(e0[r] - rmx[r]) / rsm[r];
                csum[0] += a0; p[r] = (f16)a0;
            }
            *(f16x4*)&attn_s[buf][row][wave * 16 + kq * 4] = p;
        }
        {
            f16x4 p;
#pragma unroll
            for (int r = 0; r < 4; ++r) {
                float a0 = __expf(e1[r] - rmx[r]) / rsm[r];
                csum[1] += a0; p[r] = (f16)a0;
            }
            *(f16x4*)&attn_s[buf][16 + row][wave * 16 + kq * 4] = p;
        }
        __syncthreads();
        // prefetch energy(it+1) operand loads
        const bool more = (it + 1) < NDIM / 64;
        f16x8 Afp[8];
        if (more) {
            const int nb4 = (it + 1) * 4 + wave;
#pragma unroll
            for (int k = 0; k < 8; ++k)
                Afp[k] = *(const f16x8*)&ytb[((nb4 * 8 + k) << 9) + lo];
        }
        // PV(it): this wave owns c in [wave*64, wave*64+64)
#pragma unroll
        for (int ks = 0; ks < 2; ++ks) {
            f16x8 Bp0 = *(const f16x8*)&attn_s[buf][row][ks * 32 + kq * 8];
            f16x8 Bp1 = *(const f16x8*)&attn_s[buf][16 + row][ks * 32 + kq * 8];
#pragma unroll
            for (int cc = 0; cc < 4; ++cc) {
                f16x8 Ap = *(const f16x8*)&vhb[(((wave * 4 + cc) * 64 + it * 2 + ks) << 9) + lo];
                xacc[cc][0] = mfma16(Ap, Bp0, xacc[cc][0]);
                xacc[cc][1] = mfma16(Ap, Bp1, xacc[cc][1]);
            }
        }
        // energy(it+1) MFMA
        if (more) {
            e0 = (f32x4){0.f, 0.f, 0.f, 0.f};
            e1 = (f32x4){0.f, 0.f, 0.f, 0.f};
#pragma unroll
            for (int k = 0; k < 8; ++k) {
                e0 = mfma16(Afp[k], Bf[0][k], e0);
                e1 = mfma16(Afp[k], Bf[1][k], e1);
            }
        }
    }
#pragma unroll
    for (int off = 16; off <= 32; off <<= 1)
#pragma unroll
        for (int mm = 0; mm < 2; ++mm) csum[mm] += __shfl_xor(csum[mm], off);
    if (lane < 16) {
#pragma unroll
        for (int mm = 0; mm < 2; ++mm) cred[wave][mm * 16 + lane] = csum[mm];
    }
    __syncthreads();
    if (threadIdx.x < 32) {
        float s = 0.f;
#pragma unroll
        for (int w = 0; w < 4; ++w) s += cred[w][threadIdx.x];
        cinv[threadIdx.x] = 1.f / (1e-9f + s);
    }
    __syncthreads();
    const f16* xtb = xt + (size_t)b * NDIM * CDIM;
    f16* dhb = dh + (size_t)b * NDIM * CDIM;
#pragma unroll
    for (int mm = 0; mm < 2; ++mm) {
        float ci = cinv[mm * 16 + row];
#pragma unroll
        for (int cc = 0; cc < 4; ++cc) {
            const int c = wave * 64 + cc * 16 + kq * 4;
            const size_t idx = ((size_t)((mt * 2 + mm) * 8 + (c >> 5)) << 9)
                               + row * 32 + (c & 31);
            f16x4 xv = *(const f16x4*)&xtb[idx];
            f16x4 p;
#pragma unroll
            for (int r = 0; r < 4; ++r)
                p[r] = (f16)((float)xv[r] - xacc[cc][mm][r] * ci);
            *(f16x4*)&dhb[idx] = p;
        }
    }
}

// ---------------------------------------------------------------------------
// K4a (MFMA): t = Wt*d + bt ; bn ; feat = x + relu(bn). Tiled operands.
// ---------------------------------------------------------------------------
__global__ __launch_bounds__(256)
void k_tbn(const float* __restrict__ x, const f16* __restrict__ dh,
           const f16* __restrict__ wth, const float* __restrict__ bt,
           const float* __restrict__ gamma, const float* __restrict__ beta,
           float* __restrict__ feat)
{
    const int id = blockIdx.x;
    const int b = id & 7, nt = (id >> 3) & 31, ct = id >> 8;
    const int wave = threadIdx.x >> 6, lane = threadIdx.x & 63;
    const int row = lane & 15, kq = lane >> 4;
    const int lo = row * 32 + kq * 8;
    const int n0 = nt * 64;
    const int ot = ct * 4 + wave;
    const f16* db = dh + (size_t)b * NDIM * CDIM;
    f32x4 acc[4];
#pragma unroll
    for (int j = 0; j < 4; ++j) acc[j] = (f32x4){0.f, 0.f, 0.f, 0.f};
#pragma unroll
    for (int k = 0; k < 8; ++k) {
        f16x8 A = *(const f16x8*)&wth[((ot * 8 + k) << 9) + lo];
#pragma unroll
        for (int j = 0; j < 4; ++j) {
            f16x8 B = *(const f16x8*)&db[(((nt * 4 + j) * 8 + k) << 9) + lo];
            acc[j] = mfma16(A, B, acc[j]);
        }
    }
    const float bnsc = 0.99999500003749968f; // 1/sqrt(1 + 1e-5)
    const int o0 = ot * 16;
#pragma unroll
    for (int j = 0; j < 4; ++j) {
        const int n = n0 + j * 16 + row;
#pragma unroll
        for (int r = 0; r < 4; ++r) {
            const int o = o0 + kq * 4 + r;
            float t = acc[j][r] + bt[o];
            float bn = t * bnsc * gamma[o] + beta[o];
            size_t off = ((size_t)b * CDIM + o) * NDIM + n;
            feat[off] = x[off] + fmaxf(bn, 0.f);
        }
    }
}

// ---------------------------------------------------------------------------
// K4b: query = Wproj*feat + bproj
// ---------------------------------------------------------------------------
__global__ __launch_bounds__(256)
void k_query(const float* __restrict__ feat, const float* __restrict__ Wp,
             const float* __restrict__ bp, float* __restrict__ query)
{
    __shared__ float wp_s[3 * CDIM];
    const int tid = threadIdx.x, b = blockIdx.y;
    for (int i = tid; i < 3 * CDIM; i += 256) wp_s[i] = Wp[i];
    __syncthreads();
    const int n = blockIdx.x * 256 + tid;
    float a0 = 0.f, a1 = 0.f, a2 = 0.f;
    const float* fb = feat + (size_t)b * CDIM * NDIM + n;
    for (int c = 0; c < CDIM; ++c) {
        float f = fb[(size_t)c * NDIM];
        a0 += wp_s[c] * f;
        a1 += wp_s[CDIM + c] * f;
        a2 += wp_s[2 * CDIM + c] * f;
    }
    query[((size_t)b * 3 + 0) * NDIM + n] = a0 + bp[0];
    query[((size_t)b * 3 + 1) * NDIM + n] = a1 + bp[1];
    query[((size_t)b * 3 + 2) * NDIM + n] = a2 + bp[2];
}

// ---------------------------------------------------------------------------
// K5: one wave per query; lane scans 64 pts; 64-lane tournament merge.
// ---------------------------------------------------------------------------
__global__ __launch_bounds__(256)
void k_softproj(const float4* __restrict__ pt4, const float* __restrict__ query,
                const float* __restrict__ temp_p, float* __restrict__ out)
{
    const int wave = threadIdx.x >> 6, lane = threadIdx.x & 63;
    const int b = blockIdx.y;
    const int n = blockIdx.x * 4 + wave;
    const float4* ptb = pt4 + (size_t)b * MDIM;
    const float qx = query[((size_t)b * 3 + 0) * NDIM + n];
    const float qy = query[((size_t)b * 3 + 1) * NDIM + n];
    const float qz = query[((size_t)b * 3 + 2) * NDIM + n];
    const float q2 = qx * qx + qy * qy + qz * qz;

    float bd[KNN];
    int bi[KNN];
#pragma unroll
    for (int k = 0; k < KNN; ++k) { bd[k] = 3.4e38f; bi[k] = 0x7fffffff; }
#pragma unroll 4
    for (int i = 0; i < MDIM / 64; ++i) {
        const int m = i * 64 + lane;
        float4 p = ptb[m];
        float d2 = q2 + p.w - 2.0f * (qx * p.x + qy * p.y + qz * p.z);
        if (d2 < bd[KNN - 1]) {
            bd[KNN - 1] = d2; bi[KNN - 1] = m;
#pragma unroll
            for (int k = KNN - 1; k > 0; --k) {
                bool sw = bd[k] < bd[k - 1];
                float td = sw ? bd[k - 1] : bd[k];
                bd[k - 1] = sw ? bd[k] : bd[k - 1];
                bd[k] = td;
                int ti = sw ? bi[k - 1] : bi[k];
                bi[k - 1] = sw ? bi[k] : bi[k - 1];
                bi[k] = ti;
            }
        }
    }
    int wi[KNN];
#pragma unroll
    for (int k = 0; k < KNN; ++k) {
        float d = bd[0];
        int idx = bi[0];
#pragma unroll
        for (int off = 1; off <= 32; off <<= 1) {
            float od = __shfl_xor(d, off);
            int oi = __shfl_xor(idx, off);
            if (od < d || (od == d && oi < idx)) { d = od; idx = oi; }
        }
        wi[k] = idx;
        bool won = (bd[0] == d) && (bi[0] == idx);
#pragma unroll
        for (int s = 0; s < KNN - 1; ++s) {
            bd[s] = won ? bd[s + 1] : bd[s];
            bi[s] = won ? bi[s + 1] : bi[s];
        }
        if (won) { bd[KNN - 1] = 3.4e38f; bi[KNN - 1] = 0x7fffffff; }
    }
    const float temp = temp_p[0];
    const float sigma = fmaxf(temp * temp, 1e-4f) + 1e-8f;
    const float inv_sig = 1.0f / sigma;
    float gx[KNN], gy[KNN], gz[KNN], dist[KNN];
#pragma unroll
    for (int k = 0; k < KNN; ++k) {
        float4 p = ptb[wi[k]];
        gx[k] = p.x; gy[k] = p.y; gz[k] = p.z;
        float dx = p.x - qx, dy = p.y - qy, dz = p.z - qz;
        dist[k] = (dx * dx + dy * dy + dz * dz) * inv_sig;
    }
    float mn = dist[0];
#pragma unroll
    for (int k = 1; k < KNN; ++k) mn = fminf(mn, dist[k]);
    float wsum = 0.f, ox = 0.f, oy = 0.f, oz = 0.f;
#pragma unroll
    for (int k = 0; k < KNN; ++k) {
        float w = __expf(mn - dist[k]);
        wsum += w; ox += w * gx[k]; oy += w * gy[k]; oz += w * gz[k];
    }
    if (lane == 0) {
        float invw = 1.0f / wsum;
        out[((size_t)b * 3 + 0) * NDIM + n] = ox * invw;
        out[((size_t)b * 3 + 1) * NDIM + n] = oy * invw;
        out[((size_t)b * 3 + 2) * NDIM + n] = oz * invw;
    }
}

// ---------------------------------------------------------------------------
extern "C" void kernel_launch(void* const* d_in, const int* in_sizes, int n_in,
                              void* d_out, int out_size, void* d_ws, size_t ws_size,
                              hipStream_t stream)
{
    const float* x     = (const float*)d_in[0];
    const float* pc    = (const float*)d_in[1];
    const float* Wqk   = (const float*)d_in[2];
    const float* Wv    = (const float*)d_in[3];
    const float* bv    = (const float*)d_in[4];
    const float* Wt    = (const float*)d_in[5];
    const float* bt    = (const float*)d_in[6];
    const float* gamma = (const float*)d_in[7];
    const float* beta  = (const float*)d_in[8];
    const float* Wp    = (const float*)d_in[9];
    const float* bp    = (const float*)d_in[10];
    const float* temp  = (const float*)d_in[11];
    float* out = (float*)d_out;

    char* w = (char*)d_ws;
    const size_t MB = 1024 * 1024;
    f16*    yt     = (f16*)(w);               // 8 MB tiled [n/16][c/32]
    f16*    vh     = (f16*)(w + 8 * MB);      // 8 MB tiled [c/16][n/32]
    f16*    dh     = (f16*)(w + 16 * MB);     // 8 MB tiled [n/16][c/32]
    f16*    xt     = (f16*)(w + 24 * MB);     // 8 MB tiled [n/16][c/32]
    f16*    wqh    = (f16*)(w + 32 * MB);     // 128 KB tiled
    f16*    wvh    = wqh + 65536;
    f16*    wth    = wvh + 65536;
    float4* pt4    = (float4*)(w + 33 * MB);  // 512 KB
    float*  diag   = (float*)(w + 34 * MB);   // 64 KB
    float*  rowsum = diag + (size_t)BDIM * NDIM;
    float*  query  = rowsum + (size_t)BDIM * NDIM;
    float*  feat   = (float*)(w);             // 16 MB, aliases yt+vh (dead)

    k_prep_w<<<dim3(256), 256, 0, stream>>>(Wqk, Wv, Wt, wqh, wvh, wth);
    k_prep_pt<<<dim3(128), 256, 0, stream>>>(pc, pt4);
    k_xt<<<dim3(NDIM / 64, CDIM / 64, BDIM), 256, 0, stream>>>(x, xt);
    k_qkv<<<dim3(1024), 256, 0, stream>>>(xt, wqh, wvh, bv, yt, vh);
    k_ynorm<<<dim3(BDIM * NDIM / 4), 256, 0, stream>>>(yt, diag);
    k_rowstats<<<dim3(512), 256, 0, stream>>>(yt, diag, rowsum);
    k_attn_xr<<<dim3(512), 256, 0, stream>>>(yt, vh, diag, rowsum, xt, dh);
    k_tbn<<<dim3(1024), 256, 0, stream>>>(x, dh, wth, bt, gamma, beta, feat);
    k_query<<<dim3(NDIM / 256, BDIM), 256, 0, stream>>>(feat, Wp, bp, query);
    k_softproj<<<dim3(NDIM / 4, BDIM), 256, 0, stream>>>(pt4, query, temp, out);
}

// Round 7
// 342.841 us; speedup vs baseline: 6.1108x; 1.1466x over previous
//
#include <hip/hip_runtime.h>
#include <math.h>

#define BDIM 8
#define CDIM 256
#define NDIM 2048
#define MDIM 4096
#define KNN 10

typedef _Float16 f16;
typedef f16  f16x8 __attribute__((ext_vector_type(8)));
typedef f16  f16x4 __attribute__((ext_vector_type(4)));
typedef float f32x4 __attribute__((ext_vector_type(4)));

__device__ __forceinline__ f32x4 mfma16(f16x8 a, f16x8 b, f32x4 c) {
    return __builtin_amdgcn_mfma_f32_16x16x32_f16(a, b, c, 0, 0, 0);
}

// Tiled fp16 layout: T[R/16][K/32][16][32]; element (r,k) at
// ((r>>4)*(K/32) + (k>>5))*512 + (r&15)*32 + (k&31).
// MFMA A/B fragment = contiguous 1KB: lane(row,kq) reads 16B at
// tile*512 + row*32 + kq*8.

// ---------------------------------------------------------------------------
// P1: weights -> fp16 tiled [o/16][c/32][16][32]
// ---------------------------------------------------------------------------
__global__ __launch_bounds__(256)
void k_prep_w(const float* __restrict__ Wqk, const float* __restrict__ Wv,
              const float* __restrict__ Wt,
              f16* __restrict__ wqh, f16* __restrict__ wvh, f16* __restrict__ wth)
{
    int i = blockIdx.x * 256 + threadIdx.x;
    int o = i >> 8, c = i & 255;
    int idx = (((o >> 4) * 8 + (c >> 5)) << 9) + (o & 15) * 32 + (c & 31);
    wqh[idx] = (f16)Wqk[i];
    wvh[idx] = (f16)Wv[i];
    wth[idx] = (f16)Wt[i];
}

// ---------------------------------------------------------------------------
// P2: pt4[b][m] = (x, y, z, |p|^2)
// ---------------------------------------------------------------------------
__global__ __launch_bounds__(256)
void k_prep_pt(const float* __restrict__ pc, float4* __restrict__ pt4)
{
    int i = blockIdx.x * 256 + threadIdx.x;
    int b = i >> 12, m = i & (MDIM - 1);
    const float* pb = pc + (size_t)b * 3 * MDIM;
    float a = pb[m], c = pb[MDIM + m], d = pb[2 * MDIM + m];
    pt4[i] = make_float4(a, c, d, a * a + c * c + d * d);
}

// ---------------------------------------------------------------------------
// P3: xt = fp16(x^T) in tiled layout [n/16][c/32][16][32] per batch
// ---------------------------------------------------------------------------
__global__ __launch_bounds__(256)
void k_xt(const float* __restrict__ x, f16* __restrict__ xt)
{
    __shared__ float ls[64][68];
    const int nt = blockIdx.x, ct = blockIdx.y, b = blockIdx.z;
    const int tid = threadIdx.x;
    const int n0 = nt * 64, c0 = ct * 64;
    const int cl = tid >> 4, n4 = (tid & 15) * 4;
#pragma unroll
    for (int q = 0; q < 4; ++q) {
        int c = q * 16 + cl;
        *(float4*)&ls[c][n4] = *(const float4*)&x[((size_t)b * CDIM + c0 + c) * NDIM + n0 + n4];
    }
    __syncthreads();
    f16* xb = xt + (size_t)b * NDIM * CDIM;
    const int c4 = (tid & 15) * 4;
    const int cg = c0 + c4;
#pragma unroll
    for (int q = 0; q < 4; ++q) {
        f16x4 p;
#pragma unroll
        for (int r = 0; r < 4; ++r) p[r] = (f16)ls[c4 + r][q * 16 + cl];
        *(f16x4*)&xb[(((nt * 4 + q) * 8 + (cg >> 5)) << 9) + cl * 32 + (cg & 31)] = p;
    }
}

// ---------------------------------------------------------------------------
// K1 (MFMA): y = Wqk*x ; v = Wv*x + bv.  grid 1024 1-D: b = id&7.
// ---------------------------------------------------------------------------
__global__ __launch_bounds__(256)
void k_qkv(const f16* __restrict__ xt, const f16* __restrict__ wqh,
           const f16* __restrict__ wvh, const float* __restrict__ bv,
           f16* __restrict__ yt, f16* __restrict__ vh)
{
    const int id = blockIdx.x;
    const int b = id & 7, nt = (id >> 3) & 31, ct = id >> 8;
    const int wave = threadIdx.x >> 6, lane = threadIdx.x & 63;
    const int row = lane & 15, kq = lane >> 4;
    const int lo = row * 32 + kq * 8;
    const int n0 = nt * 64;
    const int ot = ct * 4 + wave;                 // o-tile (o0 = ot*16)
    const f16* xb = xt + (size_t)b * NDIM * CDIM;
    f16* ytb = yt + (size_t)b * NDIM * CDIM;
    f16* vhb = vh + (size_t)b * CDIM * NDIM;
    f32x4 accy[4], accv[4];
#pragma unroll
    for (int j = 0; j < 4; ++j) {
        accy[j] = (f32x4){0.f, 0.f, 0.f, 0.f};
        accv[j] = (f32x4){0.f, 0.f, 0.f, 0.f};
    }
#pragma unroll
    for (int k = 0; k < 8; ++k) {
        f16x8 Aq = *(const f16x8*)&wqh[((ot * 8 + k) << 9) + lo];
        f16x8 Av = *(const f16x8*)&wvh[((ot * 8 + k) << 9) + lo];
#pragma unroll
        for (int j = 0; j < 4; ++j) {
            f16x8 Bx = *(const f16x8*)&xb[((((nt * 4) + j) * 8 + k) << 9) + lo];
            accy[j] = mfma16(Aq, Bx, accy[j]);
            accv[j] = mfma16(Av, Bx, accv[j]);
        }
    }
    const int o0 = ot * 16;
    const int yin = (o0 & 31) + kq * 4;
#pragma unroll
    for (int j = 0; j < 4; ++j) {
        f16x4 p;
#pragma unroll
        for (int r = 0; r < 4; ++r) p[r] = (f16)accy[j][r];
        *(f16x4*)&ytb[((((nt * 4) + j) * 8 + (o0 >> 5)) << 9) + row * 32 + yin] = p;
#pragma unroll
        for (int r = 0; r < 4; ++r) {
            const int o = o0 + kq * 4 + r;
            const int n = n0 + j * 16 + row;
            vhb[((ot * 64 + (n >> 5)) << 9) + (kq * 4 + r) * 32 + (n & 31)] =
                (f16)(accv[j][r] + bv[o]);
        }
    }
}

// ---------------------------------------------------------------------------
// K1b: diag[b][n] = |y_n|^2
// ---------------------------------------------------------------------------
__global__ __launch_bounds__(256)
void k_ynorm(const f16* __restrict__ yt, float* __restrict__ diag)
{
    const int wave = threadIdx.x >> 6, lane = threadIdx.x & 63;
    const int id = blockIdx.x * 4 + wave;
    const int n = id & (NDIM - 1);
    const f16* base = yt + (size_t)(id >> 11) * NDIM * CDIM;
    f16x4 p = *(const f16x4*)&base[(((n >> 4) * 8 + (lane >> 3)) << 9)
                                   + (n & 15) * 32 + (lane & 7) * 4];
    float s = 0.f;
#pragma unroll
    for (int r = 0; r < 4; ++r) { float v = (float)p[r]; s += v * v; }
#pragma unroll
    for (int off = 1; off <= 32; off <<= 1) s += __shfl_xor(s, off);
    if (lane == 0) diag[id] = s;
}

// ---------------------------------------------------------------------------
// K2 (MFMA): rowsum[m] = sum_n exp(E[m][n] - diag[m]).
// 512 threads (8 waves, 4 waves/SIMD), y m-tile staged in LDS.
// grid 512: b = id&7.
// ---------------------------------------------------------------------------
__global__ __launch_bounds__(512, 4)
void k_rowstats(const f16* __restrict__ yt, const float* __restrict__ diag,
                float* __restrict__ rowsum)
{
    const int id = blockIdx.x;
    const int b = id & 7, mt = id >> 3;                // m0 = mt*32
    const int wave = threadIdx.x >> 6, lane = threadIdx.x & 63;
    const int row = lane & 15, kq = lane >> 4;
    const int lo = row * 32 + kq * 8;
    const f16* ytb = yt + (size_t)b * NDIM * CDIM;
    __shared__ __align__(16) f16 ybf[8192];            // 32 m x 256 c = 16 KB
    __shared__ float ssm[8][32];
    {
        const f16* ysrc = ytb + ((size_t)(mt * 16) << 9);
        *(f16x8*)&ybf[threadIdx.x * 8] = *(const f16x8*)&ysrc[threadIdx.x * 8];
        *(f16x8*)&ybf[4096 + threadIdx.x * 8] = *(const f16x8*)&ysrc[4096 + threadIdx.x * 8];
    }
    const float dmx0 = diag[(size_t)b * NDIM + mt * 32 + row];
    const float dmx1 = diag[(size_t)b * NDIM + mt * 32 + 16 + row];
    __syncthreads();
    float sm0 = 0.f, sm1 = 0.f;
    for (int it = wave; it < NDIM / 16; it += 8) {
        f16x8 A[8];
#pragma unroll
        for (int k = 0; k < 8; ++k)
            A[k] = *(const f16x8*)&ytb[((it * 8 + k) << 9) + lo];
        f32x4 a0 = {0.f, 0.f, 0.f, 0.f}, a1 = {0.f, 0.f, 0.f, 0.f};
#pragma unroll
        for (int k = 0; k < 8; ++k) {
            f16x8 b0 = *(const f16x8*)&ybf[(k << 9) + lo];
            f16x8 b1 = *(const f16x8*)&ybf[((8 + k) << 9) + lo];
            a0 = mfma16(A[k], b0, a0);
            a1 = mfma16(A[k], b1, a1);
        }
#pragma unroll
        for (int r = 0; r < 4; ++r) {
            sm0 += __expf(a0[r] - dmx0);
            sm1 += __expf(a1[r] - dmx1);
        }
    }
#pragma unroll
    for (int off = 16; off <= 32; off <<= 1) {
        sm0 += __shfl_xor(sm0, off);
        sm1 += __shfl_xor(sm1, off);
    }
    if (lane < 16) {
        ssm[wave][lane] = sm0;
        ssm[wave][16 + lane] = sm1;
    }
    __syncthreads();
    if (threadIdx.x < 32) {
        float S = 0.f;
#pragma unroll
        for (int w = 0; w < 8; ++w) S += ssm[w][threadIdx.x];
        rowsum[(size_t)b * NDIM + mt * 32 + threadIdx.x] = S;
    }
}

// ---------------------------------------------------------------------------
// K3 (MFMA): energy -> attn -> PV.  512 threads (8 waves, 4/SIMD), y m-tile
// in LDS, 128-n iterations, dbuf attn, all 16 fragment loads batched after
// the barrier. Epilogue: dh = fp16(x - xr), tiled. grid 512: b = id&7.
// ---------------------------------------------------------------------------
__global__ __launch_bounds__(512, 4)
void k_attn_xr(const f16* __restrict__ yt, const f16* __restrict__ vh,
               const float* __restrict__ diag, const float* __restrict__ rowsum,
               const f16* __restrict__ xt, f16* __restrict__ dh)
{
    const int id = blockIdx.x;
    const int b = id & 7, mt = id >> 3;                // m0 = mt*32
    const int wave = threadIdx.x >> 6, lane = threadIdx.x & 63;
    const int row = lane & 15, kq = lane >> 4;
    const int lo = row * 32 + kq * 8;
    const f16* ytb = yt + (size_t)b * NDIM * CDIM;
    const f16* vhb = vh + (size_t)b * CDIM * NDIM;
    const float* dgb = diag + (size_t)b * NDIM;
    const float* rsb = rowsum + (size_t)b * NDIM;
    __shared__ __align__(16) f16 ybf[8192];            // y m-tile, 16 KB
    __shared__ __align__(16) f16 attn_s[2][32][136];   // dbuf, 17.4 KB
    __shared__ float cred[8][32];
    __shared__ float cinv[32];
    {
        const f16* ysrc = ytb + ((size_t)(mt * 16) << 9);
        *(f16x8*)&ybf[threadIdx.x * 8] = *(const f16x8*)&ysrc[threadIdx.x * 8];
        *(f16x8*)&ybf[4096 + threadIdx.x * 8] = *(const f16x8*)&ysrc[4096 + threadIdx.x * 8];
    }
    // prefetch energy A-frags for iteration 0 (n = wave*16)
    f16x8 Af[8];
#pragma unroll
    for (int k = 0; k < 8; ++k)
        Af[k] = *(const f16x8*)&ytb[((wave * 8 + k) << 9) + lo];
    __syncthreads();
    f32x4 e0 = {0.f, 0.f, 0.f, 0.f}, e1 = {0.f, 0.f, 0.f, 0.f};
#pragma unroll
    for (int k = 0; k < 8; ++k) {
        f16x8 b0 = *(const f16x8*)&ybf[(k << 9) + lo];
        f16x8 b1 = *(const f16x8*)&ybf[((8 + k) << 9) + lo];
        e0 = mfma16(Af[k], b0, e0);
        e1 = mfma16(Af[k], b1, e1);
    }
    f32x4 xacc[2][2];
#pragma unroll
    for (int cc = 0; cc < 2; ++cc)
#pragma unroll
        for (int mm = 0; mm < 2; ++mm) xacc[cc][mm] = (f32x4){0.f, 0.f, 0.f, 0.f};
    float csum[2] = {0.f, 0.f};

    for (int it = 0; it < NDIM / 128; ++it) {
        const int buf = it & 1;
        const int nb = it * 128 + wave * 16;
        f32x4 rmx = *(const f32x4*)&dgb[nb + kq * 4];
        f32x4 rsm = *(const f32x4*)&rsb[nb + kq * 4];
        {
            f16x4 p;
#pragma unroll
            for (int r = 0; r < 4; ++r) {
                float a0 = __expf(e0[r] - rmx[r]) / rsm[r];
                csum[0] += a0; p[r] = (f16)a0;
            }
            *(f16x4*)&attn_s[buf][row][wave * 16 + kq * 4] = p;
        }
        {
            f16x4 p;
#pragma unroll
            for (int r = 0; r < 4; ++r) {
                float a0 = __expf(e1[r] - rmx[r]) / rsm[r];
                csum[1] += a0; p[r] = (f16)a0;
            }
            *(f16x4*)&attn_s[buf][16 + row][wave * 16 + kq * 4] = p;
        }
        __syncthreads();
        const bool more = (it + 1) < NDIM / 128;
        // batched fragment loads: PV operands first, then next-iter energy
        f16x8 Ap[8];
#pragma unroll
        for (int ks = 0; ks < 4; ++ks)
#pragma unroll
            for (int cc = 0; cc < 2; ++cc)
                Ap[ks * 2 + cc] = *(const f16x8*)
                    &vhb[((((wave * 2 + cc) * 64) + it * 4 + ks) << 9) + lo];
        if (more) {
#pragma unroll
            for (int k = 0; k < 8; ++k)
                Af[k] = *(const f16x8*)&ytb[((((it + 1) * 8 + wave) * 8 + k) << 9) + lo];
        }
        // PV(it): this wave owns c in [wave*32, wave*32+32)
#pragma unroll
        for (int ks = 0; ks < 4; ++ks) {
            f16x8 Bp0 = *(const f16x8*)&attn_s[buf][row][ks * 32 + kq * 8];
            f16x8 Bp1 = *(const f16x8*)&attn_s[buf][16 + row][ks * 32 + kq * 8];
#pragma unroll
            for (int cc = 0; cc < 2; ++cc) {
                xacc[cc][0] = mfma16(Ap[ks * 2 + cc], Bp0, xacc[cc][0]);
                xacc[cc][1] = mfma16(Ap[ks * 2 + cc], Bp1, xacc[cc][1]);
            }
        }
        // energy(it+1)
        if (more) {
            e0 = (f32x4){0.f, 0.f, 0.f, 0.f};
            e1 = (f32x4){0.f, 0.f, 0.f, 0.f};
#pragma unroll
            for (int k = 0; k < 8; ++k) {
                f16x8 b0 = *(const f16x8*)&ybf[(k << 9) + lo];
                f16x8 b1 = *(const f16x8*)&ybf[((8 + k) << 9) + lo];
                e0 = mfma16(Af[k], b0, e0);
                e1 = mfma16(Af[k], b1, e1);
            }
        }
    }
#pragma unroll
    for (int off = 16; off <= 32; off <<= 1)
#pragma unroll
        for (int mm = 0; mm < 2; ++mm) csum[mm] += __shfl_xor(csum[mm], off);
    if (lane < 16) {
        cred[wave][lane] = csum[0];
        cred[wave][16 + lane] = csum[1];
    }
    __syncthreads();
    if (threadIdx.x < 32) {
        float s = 0.f;
#pragma unroll
        for (int w = 0; w < 8; ++w) s += cred[w][threadIdx.x];
        cinv[threadIdx.x] = 1.f / (1e-9f + s);
    }
    __syncthreads();
    const f16* xtb = xt + (size_t)b * NDIM * CDIM;
    f16* dhb = dh + (size_t)b * NDIM * CDIM;
#pragma unroll
    for (int mm = 0; mm < 2; ++mm) {
        float ci = cinv[mm * 16 + row];
#pragma unroll
        for (int cc = 0; cc < 2; ++cc) {
            const int cin = cc * 16 + kq * 4;          // c = wave*32 + cin
            const size_t idx = ((size_t)((mt * 2 + mm) * 8 + wave) << 9)
                               + row * 32 + cin;
            f16x4 xv = *(const f16x4*)&xtb[idx];
            f16x4 p;
#pragma unroll
            for (int r = 0; r < 4; ++r)
                p[r] = (f16)((float)xv[r] - xacc[cc][mm][r] * ci);
            *(f16x4*)&dhb[idx] = p;
        }
    }
}

// ---------------------------------------------------------------------------
// K4a (MFMA): t = Wt*d + bt ; bn ; feat = x + relu(bn). Tiled operands.
// ---------------------------------------------------------------------------
__global__ __launch_bounds__(256)
void k_tbn(const float* __restrict__ x, const f16* __restrict__ dh,
           const f16* __restrict__ wth, const float* __restrict__ bt,
           const float* __restrict__ gamma, const float* __restrict__ beta,
           float* __restrict__ feat)
{
    const int id = blockIdx.x;
    const int b = id & 7, nt = (id >> 3) & 31, ct = id >> 8;
    const int wave = threadIdx.x >> 6, lane = threadIdx.x & 63;
    const int row = lane & 15, kq = lane >> 4;
    const int lo = row * 32 + kq * 8;
    const int n0 = nt * 64;
    const int ot = ct * 4 + wave;
    const f16* db = dh + (size_t)b * NDIM * CDIM;
    f32x4 acc[4];
#pragma unroll
    for (int j = 0; j < 4; ++j) acc[j] = (f32x4){0.f, 0.f, 0.f, 0.f};
#pragma unroll
    for (int k = 0; k < 8; ++k) {
        f16x8 A = *(const f16x8*)&wth[((ot * 8 + k) << 9) + lo];
#pragma unroll
        for (int j = 0; j < 4; ++j) {
            f16x8 B = *(const f16x8*)&db[(((nt * 4 + j) * 8 + k) << 9) + lo];
            acc[j] = mfma16(A, B, acc[j]);
        }
    }
    const float bnsc = 0.99999500003749968f; // 1/sqrt(1 + 1e-5)
    const int o0 = ot * 16;
#pragma unroll
    for (int j = 0; j < 4; ++j) {
        const int n = n0 + j * 16 + row;
#pragma unroll
        for (int r = 0; r < 4; ++r) {
            const int o = o0 + kq * 4 + r;
            float t = acc[j][r] + bt[o];
            float bn = t * bnsc * gamma[o] + beta[o];
            size_t off = ((size_t)b * CDIM + o) * NDIM + n;
            feat[off] = x[off] + fmaxf(bn, 0.f);
        }
    }
}

// ---------------------------------------------------------------------------
// K4b: query = Wproj*feat + bproj
// ---------------------------------------------------------------------------
__global__ __launch_bounds__(256)
void k_query(const float* __restrict__ feat, const float* __restrict__ Wp,
             const float* __restrict__ bp, float* __restrict__ query)
{
    __shared__ float wp_s[3 * CDIM];
    const int tid = threadIdx.x, b = blockIdx.y;
    for (int i = tid; i < 3 * CDIM; i += 256) wp_s[i] = Wp[i];
    __syncthreads();
    const int n = blockIdx.x * 256 + tid;
    float a0 = 0.f, a1 = 0.f, a2 = 0.f;
    const float* fb = feat + (size_t)b * CDIM * NDIM + n;
    for (int c = 0; c < CDIM; ++c) {
        float f = fb[(size_t)c * NDIM];
        a0 += wp_s[c] * f;
        a1 += wp_s[CDIM + c] * f;
        a2 += wp_s[2 * CDIM + c] * f;
    }
    query[((size_t)b * 3 + 0) * NDIM + n] = a0 + bp[0];
    query[((size_t)b * 3 + 1) * NDIM + n] = a1 + bp[1];
    query[((size_t)b * 3 + 2) * NDIM + n] = a2 + bp[2];
}

// ---------------------------------------------------------------------------
// K5: one wave per query; lane scans 64 pts; 64-lane tournament merge.
// ---------------------------------------------------------------------------
__global__ __launch_bounds__(256)
void k_softproj(const float4* __restrict__ pt4, const float* __restrict__ query,
                const float* __restrict__ temp_p, float* __restrict__ out)
{
    const int wave = threadIdx.x >> 6, lane = threadIdx.x & 63;
    const int b = blockIdx.y;
    const int n = blockIdx.x * 4 + wave;
    const float4* ptb = pt4 + (size_t)b * MDIM;
    const float qx = query[((size_t)b * 3 + 0) * NDIM + n];
    const float qy = query[((size_t)b * 3 + 1) * NDIM + n];
    const float qz = query[((size_t)b * 3 + 2) * NDIM + n];
    const float q2 = qx * qx + qy * qy + qz * qz;

    float bd[KNN];
    int bi[KNN];
#pragma unroll
    for (int k = 0; k < KNN; ++k) { bd[k] = 3.4e38f; bi[k] = 0x7fffffff; }
#pragma unroll 4
    for (int i = 0; i < MDIM / 64; ++i) {
        const int m = i * 64 + lane;
        float4 p = ptb[m];
        float d2 = q2 + p.w - 2.0f * (qx * p.x + qy * p.y + qz * p.z);
        if (d2 < bd[KNN - 1]) {
            bd[KNN - 1] = d2; bi[KNN - 1] = m;
#pragma unroll
            for (int k = KNN - 1; k > 0; --k) {
                bool sw = bd[k] < bd[k - 1];
                float td = sw ? bd[k - 1] : bd[k];
                bd[k - 1] = sw ? bd[k] : bd[k - 1];
                bd[k] = td;
                int ti = sw ? bi[k - 1] : bi[k];
                bi[k - 1] = sw ? bi[k] : bi[k - 1];
                bi[k] = ti;
            }
        }
    }
    int wi[KNN];
#pragma unroll
    for (int k = 0; k < KNN; ++k) {
        float d = bd[0];
        int idx = bi[0];
#pragma unroll
        for (int off = 1; off <= 32; off <<= 1) {
            float od = __shfl_xor(d, off);
            int oi = __shfl_xor(idx, off);
            if (od < d || (od == d && oi < idx)) { d = od; idx = oi; }
        }
        wi[k] = idx;
        bool won = (bd[0] == d) && (bi[0] == idx);
#pragma unroll
        for (int s = 0; s < KNN - 1; ++s) {
            bd[s] = won ? bd[s + 1] : bd[s];
            bi[s] = won ? bi[s + 1] : bi[s];
        }
        if (won) { bd[KNN - 1] = 3.4e38f; bi[KNN - 1] = 0x7fffffff; }
    }
    const float temp = temp_p[0];
    const float sigma = fmaxf(temp * temp, 1e-4f) + 1e-8f;
    const float inv_sig = 1.0f / sigma;
    float gx[KNN], gy[KNN], gz[KNN], dist[KNN];
#pragma unroll
    for (int k = 0; k < KNN; ++k) {
        float4 p = ptb[wi[k]];
        gx[k] = p.x; gy[k] = p.y; gz[k] = p.z;
        float dx = p.x - qx, dy = p.y - qy, dz = p.z - qz;
        dist[k] = (dx * dx + dy * dy + dz * dz) * inv_sig;
    }
    float mn = dist[0];
#pragma unroll
    for (int k = 1; k < KNN; ++k) mn = fminf(mn, dist[k]);
    float wsum = 0.f, ox = 0.f, oy = 0.f, oz = 0.f;
#pragma unroll
    for (int k = 0; k < KNN; ++k) {
        float w = __expf(mn - dist[k]);
        wsum += w; ox += w * gx[k]; oy += w * gy[k]; oz += w * gz[k];
    }
    if (lane == 0) {
        float invw = 1.0f / wsum;
        out[((size_t)b * 3 + 0) * NDIM + n] = ox * invw;
        out[((size_t)b * 3 + 1) * NDIM + n] = oy * invw;
        out[((size_t)b * 3 + 2) * NDIM + n] = oz * invw;
    }
}

// ---------------------------------------------------------------------------
extern "C" void kernel_launch(void* const* d_in, const int* in_sizes, int n_in,
                              void* d_out, int out_size, void* d_ws, size_t ws_size,
                              hipStream_t stream)
{
    const float* x     = (const float*)d_in[0];
    const float* pc    = (const float*)d_in[1];
    const float* Wqk   = (const float*)d_in[2];
    const float* Wv    = (const float*)d_in[3];
    const float* bv    = (const float*)d_in[4];
    const float* Wt    = (const float*)d_in[5];
    const float* bt    = (const float*)d_in[6];
    const float* gamma = (const float*)d_in[7];
    const float* beta  = (const float*)d_in[8];
    const float* Wp    = (const float*)d_in[9];
    const float* bp    = (const float*)d_in[10];
    const float* temp  = (const float*)d_in[11];
    float* out = (float*)d_out;

    char* w = (char*)d_ws;
    const size_t MB = 1024 * 1024;
    f16*    yt     = (f16*)(w);               // 8 MB tiled [n/16][c/32]
    f16*    vh     = (f16*)(w + 8 * MB);      // 8 MB tiled [c/16][n/32]
    f16*    dh     = (f16*)(w + 16 * MB);     // 8 MB tiled [n/16][c/32]
    f16*    xt     = (f16*)(w + 24 * MB);     // 8 MB tiled [n/16][c/32]
    f16*    wqh    = (f16*)(w + 32 * MB);     // 128 KB tiled
    f16*    wvh    = wqh + 65536;
    f16*    wth    = wvh + 65536;
    float4* pt4    = (float4*)(w + 33 * MB);  // 512 KB
    float*  diag   = (float*)(w + 34 * MB);   // 64 KB
    float*  rowsum = diag + (size_t)BDIM * NDIM;
    float*  query  = rowsum + (size_t)BDIM * NDIM;
    float*  feat   = (float*)(w);             // 16 MB, aliases yt+vh (dead)

    k_prep_w<<<dim3(256), 256, 0, stream>>>(Wqk, Wv, Wt, wqh, wvh, wth);
    k_prep_pt<<<dim3(128), 256, 0, stream>>>(pc, pt4);
    k_xt<<<dim3(NDIM / 64, CDIM / 64, BDIM), 256, 0, stream>>>(x, xt);
    k_qkv<<<dim3(1024), 256, 0, stream>>>(xt, wqh, wvh, bv, yt, vh);
    k_ynorm<<<dim3(BDIM * NDIM / 4), 256, 0, stream>>>(yt, diag);
    k_rowstats<<<dim3(512), 512, 0, stream>>>(yt, diag, rowsum);
    k_attn_xr<<<dim3(512), 512, 0, stream>>>(yt, vh, diag, rowsum, xt, dh);
    k_tbn<<<dim3(1024), 256, 0, stream>>>(x, dh, wth, bt, gamma, beta, feat);
    k_query<<<dim3(NDIM / 256, BDIM), 256, 0, stream>>>(feat, Wp, bp, query);
    k_softproj<<<dim3(NDIM / 4, BDIM), 256, 0, stream>>>(pt4, query, temp, out);
}